// Round 1
// baseline (1725.919 us; speedup 1.0000x reference)
//
#include <hip/hip_runtime.h>
#include <hip/hip_bf16.h>
#include <math.h>

// Shapes (fixed per reference): B=40, M=8, D=256, H=16x16 -> HW=256, L=15
// Blocks: 8 blocks of 5 samples. Per block: R = 2048 regions, T = 75 tokens.
#define NG 8
#define NB5 5
#define NM 8
#define NHW 256
#define NR 2048
#define ND 256
#define NL 15
#define NT 75
#define NGB 40

// workspace layout (in floats)
#define OFF_S    0                         // s [gb][t][r], aliased later as VTP [gb][m][t][d]
#define SZ_S     (NGB*NT*NR)               // 6,144,000
#define OFF_W    (OFF_S + SZ_S)            // alpha [gb][t][r]
#define OFF_RMAX (OFF_W + SZ_S)            // [gb][seg][r]
#define SZ_RST   (NGB*5*NR)                // 409,600
#define OFF_RSUM (OFF_RMAX + SZ_RST)
#define OFF_SD   (OFF_RSUM + SZ_RST)       // [gb][m][t]
#define SZ_SD    (NGB*NM*NT)
#define OFF_VNS  (OFF_SD + SZ_SD)          // [gb][m][d]
#define SZ_VNS   (NGB*NM*ND)
#define OFF_LG   (OFF_VNS + SZ_VNS)        // logit [gb][t]
#define SZ_LG    (NGB*NT)
#define OFF_LG2  (OFF_LG + SZ_LG)          // logit2 [gb][m][s]
#define SZ_LG2   (NGB*NM*5)
#define OFF_BETA (OFF_LG2 + SZ_LG2)        // [gb][m][t]
#define SZ_BETA  (NGB*NM*NT)
#define OFF_BLK  (OFF_BETA + SZ_BETA)      // [g]

__device__ __forceinline__ float bredsum(float v, float* red) {
    int tid = threadIdx.x;
    red[tid] = v; __syncthreads();
    for (int s2 = 128; s2 > 0; s2 >>= 1) {
        if (tid < s2) red[tid] += red[tid + s2];
        __syncthreads();
    }
    float r = red[0]; __syncthreads();
    return r;
}

// async global->LDS, 16B per lane, dest = wave-uniform base + lane*16
__device__ __forceinline__ void glds16(const float* g, float* l) {
    __builtin_amdgcn_global_load_lds(
        (const __attribute__((address_space(1))) void*)g,
        (__attribute__((address_space(3))) void*)l, 16, 0, 0);
}

// 20-token x float2 rank-1 FMA update (40 v_fmac)
__device__ __forceinline__ void fma20(float2 av, float4 q0, float4 q1, float4 q2,
                                      float4 q3, float4 q4, float2* acc) {
    float ev[20] = {q0.x, q0.y, q0.z, q0.w, q1.x, q1.y, q1.z, q1.w,
                    q2.x, q2.y, q2.z, q2.w, q3.x, q3.y, q3.z, q3.w,
                    q4.x, q4.y, q4.z, q4.w};
#pragma unroll
    for (int j = 0; j < 20; ++j) {
        acc[j].x += av.x * ev[j];
        acc[j].y += av.y * ev[j];
    }
}

// K1: s[gb][t][m*256+hw] = sum_d v[r][d]*e[t][d].
// grid 640 = (t-half, gb, m), 256 thr = 4 waves. Wave pairs share a 20-token
// group (t_per_wave=20 halves LDS bytes/FMA vs the old 10); lanes own an hw
// float2 half-row. A-tile staged via global_load_lds (dwordx4, double-buffered
// 16-d chunks, ONE barrier/chunk, issued a full chunk ahead); text staged via
// registers written to Et at the end of the previous chunk's compute.
// asm memory pin after each issue stops the compiler sinking the loads
// (old kernel: VGPR=68 < acc40+p32 proved the prefetch was being defeated).
__global__ __launch_bounds__(256, 3) void k1_gemm_s(const float* __restrict__ image,
                                                    const float* __restrict__ text,
                                                    float* __restrict__ ws) {
    __shared__ __align__(16) float A[2][16][256];   // [buf][dd][hw], glds-linear
    __shared__ __align__(16) float Et[2][16][44];   // [buf][dd][col], stride 44 (16B-aligned, 4-way worst)
    float* Sg = ws + OFF_S;
    int blk = blockIdx.x;
    int th = blk >= 320 ? 1 : 0;
    int rest = blk - th * 320;
    int m = rest & 7, gb = rest >> 3;
    int g = gb / 5;
    int tb = th * 40;                      // block covers t in [tb, tb+40)
    const float* cell = image + (size_t)(gb * 8 + m) * ND * NHW; // [d][hw]
    const float* tbase = text + (size_t)g * 75 * 256;
    int tid = threadIdx.x;
    int lane = tid & 63;
    int w = __builtin_amdgcn_readfirstlane(tid >> 6); // 0..3
    int w4r = w * 4;                       // glds rows w4r..w4r+3
    int hwc = (w & 1) * 128 + lane * 2;    // hw float2 base (wave-half of row)
    int qb = (w >> 1) * 24;                // Et col base for this t-group
    int edd = tid & 15, etc0 = tid >> 4;   // text staging: d-row, t-col group
    // 3 staged text values per thread: tc = etc0 + 16*I (I=0,1,2), valid tc<40
    int tc1 = etc0 + 16, tc2 = etc0 + 32;
    int te0 = tb + etc0;                         // <=55, always valid
    int te1 = tb + tc1;                          // <=71, always valid
    int te2 = tb + tc2; if (te2 > 74) te2 = 74;  // clamp (dup value, unused cols)
    bool ev2 = etc0 < 8;                         // tc2<40
    int ec0 = etc0;                              // col map: tc + (tc>=20)*4
    int ec1 = tc1 + (tc1 >= 20 ? 4 : 0);
    int ec2 = tc2 + 4;
    float2 acc[20];
#pragma unroll
    for (int j = 0; j < 20; ++j) acc[j] = make_float2(0.f, 0.f);
    float e0, e1, e2 = 0.f;
    const float* gA = cell + lane * 4;

#define K1_ISSUE(C, BUF)                                                    \
    {   int d0_ = (C) * 16;                                                 \
        glds16(gA + (size_t)(d0_ + w4r + 0) * 256, &A[BUF][w4r + 0][0]);    \
        glds16(gA + (size_t)(d0_ + w4r + 1) * 256, &A[BUF][w4r + 1][0]);    \
        glds16(gA + (size_t)(d0_ + w4r + 2) * 256, &A[BUF][w4r + 2][0]);    \
        glds16(gA + (size_t)(d0_ + w4r + 3) * 256, &A[BUF][w4r + 3][0]);    \
        e0 = tbase[(size_t)te0 * 256 + d0_ + edd];                          \
        e1 = tbase[(size_t)te1 * 256 + d0_ + edd];                          \
        if (ev2) e2 = tbase[(size_t)te2 * 256 + d0_ + edd]; }
#define K1_ETWR(BUF)                                                        \
    {   Et[BUF][edd][ec0] = e0;                                             \
        Et[BUF][edd][ec1] = e1;                                             \
        if (ev2) Et[BUF][edd][ec2] = e2; }

    K1_ISSUE(0, 0)
    K1_ETWR(0)
    asm volatile("s_waitcnt vmcnt(0)" ::: "memory");
    __syncthreads();
#pragma unroll 2
    for (int c = 0; c < 16; ++c) {
        int cur = c & 1;
        int nxt = cur ^ 1;
        if (c < 15) {
            K1_ISSUE(c + 1, nxt)
            asm volatile("" ::: "memory");   // pin load issue here (no sinking)
        }
#pragma unroll
        for (int dd = 0; dd < 16; ++dd) {
            float2 av = *(const float2*)&A[cur][dd][hwc];
            float4 q0 = *(const float4*)&Et[cur][dd][qb];
            float4 q1 = *(const float4*)&Et[cur][dd][qb + 4];
            float4 q2 = *(const float4*)&Et[cur][dd][qb + 8];
            float4 q3 = *(const float4*)&Et[cur][dd][qb + 12];
            float4 q4 = *(const float4*)&Et[cur][dd][qb + 16];
            fma20(av, q0, q1, q2, q3, q4, acc);
        }
        if (c < 15) { K1_ETWR(nxt) }         // e-loads' vmcnt wait hidden by compute
        asm volatile("s_waitcnt vmcnt(0)" ::: "memory");  // drain glds for next chunk
        __syncthreads();
    }
#undef K1_ISSUE
#undef K1_ETWR
    int tp20 = (w >> 1) * 20;
    size_t obase = (size_t)gb * 75 * 2048 + m * 256 + (w & 1) * 128 + lane * 2;
#pragma unroll
    for (int j = 0; j < 20; ++j) {
        int t = tb + tp20 + j;
        if (t < 75)
            *(float2*)&Sg[obase + (size_t)t * 2048] = acc[j];
    }
}

// K2: per-(r,seg) max/sumexp over the 15 tokens of the segment.
__global__ __launch_bounds__(256) void k2_rowstats(float* __restrict__ ws) {
    const float* Sg = ws + OFF_S;
    float* RMAX = ws + OFF_RMAX;
    float* RSUM = ws + OFF_RSUM;
    int blk = blockIdx.x;
    int m = blk & 7, gb = blk >> 3;
    int r = m * 256 + threadIdx.x;
    const float* base = Sg + (size_t)gb * 75 * 2048 + r;
    for (int seg = 0; seg < 5; ++seg) {
        float v[15]; float mx = -1e30f;
#pragma unroll
        for (int l = 0; l < 15; ++l) {
            v[l] = base[(size_t)(seg * 15 + l) * 2048];
            mx = fmaxf(mx, v[l]);
        }
        float sm = 0.f;
#pragma unroll
        for (int l = 0; l < 15; ++l) sm += __expf(v[l] - mx);
        RMAX[((size_t)gb * 5 + seg) * 2048 + r] = mx;
        RSUM[((size_t)gb * 5 + seg) * 2048 + r] = sm;
    }
}

// K3: per (gb,t) column over r=2048: colmax(s), colsum exp(s-cmax), colsum exp(s_nt);
// writes alpha (W) and per-m sums SD = sum_hw exp(p2). One pass over s.
__global__ __launch_bounds__(256) void k3_colstats(float* __restrict__ ws) {
    __shared__ float red[256];
    __shared__ float red8[8][256];
    const float* Sg = ws + OFF_S;
    const float* RMAX = ws + OFF_RMAX;
    const float* RSUM = ws + OFF_RSUM;
    float* W = ws + OFF_W;
    float* SD = ws + OFF_SD;
    int blk = blockIdx.x;           // t + 75*gb
    int t = blk % 75, gb = blk / 75;
    int seg = t / 15;
    int tid = threadIdx.x;
    const float* col = Sg + ((size_t)gb * 75 + t) * 2048;
    const float* rmx = RMAX + ((size_t)gb * 5 + seg) * 2048;
    const float* rsm = RSUM + ((size_t)gb * 5 + seg) * 2048;
    float sv[8], ent[8];
    float lmax = -1e30f, lsnt = 0.f;
#pragma unroll
    for (int k = 0; k < 8; ++k) {
        int r = tid + 256 * k;
        float s = col[r];
        sv[k] = s;
        float snt = 4.f * __expf(s - rmx[r]) / rsm[r];
        float e = __expf(snt);
        ent[k] = e;
        lsnt += e;
        lmax = fmaxf(lmax, s);
    }
    red[tid] = lmax; __syncthreads();
    for (int s2 = 128; s2 > 0; s2 >>= 1) {
        if (tid < s2) red[tid] = fmaxf(red[tid], red[tid + s2]);
        __syncthreads();
    }
    float cmax = red[0]; __syncthreads();
    float pe[8]; float lse = 0.f;
#pragma unroll
    for (int k = 0; k < 8; ++k) { pe[k] = __expf(sv[k] - cmax); lse += pe[k]; }
    float csum = bredsum(lse, red);
    float csnt = bredsum(lsnt, red);
    float inv = 1.f / csnt;
#pragma unroll
    for (int k = 0; k < 8; ++k)
        W[((size_t)gb * 75 + t) * 2048 + tid + 256 * k] = ent[k] * inv;
    float icsum = 1.f / csum;
#pragma unroll
    for (int k = 0; k < 8; ++k) red8[k][tid] = __expf(pe[k] * icsum);
    __syncthreads();
    for (int s2 = 128; s2 > 0; s2 >>= 1) {
        if (tid < s2) {
#pragma unroll
            for (int k2 = 0; k2 < 8; ++k2) red8[k2][tid] += red8[k2][tid + s2];
        }
        __syncthreads();
    }
    if (tid < 8) SD[((size_t)gb * 8 + tid) * 75 + t] = red8[tid][0];
}

// K4: v_tidal partials per m-cell: VTP[gb][m][t][d] = sum_{r in cell} alpha[r][t]*v[r][d].
// grid 640 = (t-half, gb, m), 256 thr = 4 waves; wave pairs share 20-t group,
// lanes own a d float2 half-row (t_per_wave=20). V transpose-scatter stores are
// XOR-swizzled (col ^= {0,8,16,24} by rr quadrant) -> 2-way banks (free) on
// both the scalar stores and the contiguous float2 row reads.
__global__ __launch_bounds__(256, 3) void k4_vtidal(const float* __restrict__ image,
                                                    float* __restrict__ ws) {
    __shared__ __align__(16) float V[32][256];  // [rr][d ^ SWZ(rr)]
    __shared__ __align__(16) float WtT[32][44]; // [rr][col], stride 44
    const float* W = ws + OFF_W;
    float* VTP = ws + OFF_S; // s is dead; reuse
    int blk = blockIdx.x;
    int th = blk >= 320 ? 1 : 0;
    int rest = blk - th * 320;
    int m = rest & 7, gb = rest >> 3;
    int tb = th * 40;
    const float* cell = image + (size_t)(gb * 8 + m) * ND * NHW; // [d][hw]
    int tid = threadIdx.x;
    int lane = tid & 63;
    int w = __builtin_amdgcn_readfirstlane(tid >> 6); // 0..3
    int dlc = (w & 1) * 128 + lane * 2;   // d float2 base
    int qb = (w >> 1) * 24;               // WtT col base
    int rr4 = (tid & 7) * 4;              // V rr base for this thread's float4
    int drow = tid >> 3;                  // d = drow + 32*i
    int wrr = tid & 31;                   // WtT rr
    int wtc0 = tid >> 5;                  // t-col group 0..7
#define SWZ(RR) ((((RR) & 8)) ^ ((((RR) & 4)) << 2))
    int sw0 = SWZ(rr4 + 0), sw1 = SWZ(rr4 + 1), sw2 = SWZ(rr4 + 2), sw3 = SWZ(rr4 + 3);
    float2 acc[20];
#pragma unroll
    for (int j = 0; j < 20; ++j) acc[j] = make_float2(0.f, 0.f);
    const float* wb = W + (size_t)gb * 75 * 2048 + m * 256;
    // 5 staged alpha values per thread: tc = wtc0 + 8*I, I=0..4 (tc 0..39)
    int tw0 = tb + wtc0;                               // <=47
    int tw1 = tb + wtc0 + 8;                           // <=55
    int tw2 = tb + wtc0 + 16;                          // <=63
    int tw3 = tb + wtc0 + 24;                          // <=71
    int tw4 = tb + wtc0 + 32; if (tw4 > 74) tw4 = 74;  // clamp dup
    int wc0 = wtc0;                                    // tc<20
    int wc1 = wtc0 + 8;                                // tc<20
    int wc2 = (wtc0 + 16) + ((wtc0 + 16) >= 20 ? 4 : 0);
    int wc3 = wtc0 + 24 + 4;
    int wc4 = wtc0 + 32 + 4;
    float4 p0, p1, p2, p3, p4, p5, p6, p7;
    float w0, w1, w2, w3, w4;
#define K4_LOAD(RC)                                                               \
    p0 = *(const float4*)&cell[(size_t)(drow +   0) * 256 + (RC) * 32 + rr4];     \
    p1 = *(const float4*)&cell[(size_t)(drow +  32) * 256 + (RC) * 32 + rr4];     \
    p2 = *(const float4*)&cell[(size_t)(drow +  64) * 256 + (RC) * 32 + rr4];     \
    p3 = *(const float4*)&cell[(size_t)(drow +  96) * 256 + (RC) * 32 + rr4];     \
    p4 = *(const float4*)&cell[(size_t)(drow + 128) * 256 + (RC) * 32 + rr4];     \
    p5 = *(const float4*)&cell[(size_t)(drow + 160) * 256 + (RC) * 32 + rr4];     \
    p6 = *(const float4*)&cell[(size_t)(drow + 192) * 256 + (RC) * 32 + rr4];     \
    p7 = *(const float4*)&cell[(size_t)(drow + 224) * 256 + (RC) * 32 + rr4];     \
    w0 = wb[(size_t)tw0 * 2048 + (RC) * 32 + wrr];                                \
    w1 = wb[(size_t)tw1 * 2048 + (RC) * 32 + wrr];                                \
    w2 = wb[(size_t)tw2 * 2048 + (RC) * 32 + wrr];                                \
    w3 = wb[(size_t)tw3 * 2048 + (RC) * 32 + wrr];                                \
    w4 = wb[(size_t)tw4 * 2048 + (RC) * 32 + wrr];
#define K4_VST(P, I)                                                              \
    {   int d_ = drow + 32 * (I);                                                 \
        V[rr4 + 0][d_ ^ sw0] = (P).x;                                             \
        V[rr4 + 1][d_ ^ sw1] = (P).y;                                             \
        V[rr4 + 2][d_ ^ sw2] = (P).z;                                             \
        V[rr4 + 3][d_ ^ sw3] = (P).w; }
    K4_LOAD(0)
    asm volatile("" ::: "memory");
    for (int rc = 0; rc < 8; ++rc) {
        __syncthreads();
        K4_VST(p0, 0) K4_VST(p1, 1) K4_VST(p2, 2) K4_VST(p3, 3)
        K4_VST(p4, 4) K4_VST(p5, 5) K4_VST(p6, 6) K4_VST(p7, 7)
        WtT[wrr][wc0] = w0;
        WtT[wrr][wc1] = w1;
        WtT[wrr][wc2] = w2;
        WtT[wrr][wc3] = w3;
        WtT[wrr][wc4] = w4;
        __syncthreads();
        if (rc < 7) {
            K4_LOAD(rc + 1)
            asm volatile("" ::: "memory");   // pin load issue (no sinking)
        }
#pragma unroll
        for (int rr = 0; rr < 32; ++rr) {
            float2 vv = *(const float2*)&V[rr][dlc ^ SWZ(rr)];
            float4 q0 = *(const float4*)&WtT[rr][qb];
            float4 q1 = *(const float4*)&WtT[rr][qb + 4];
            float4 q2 = *(const float4*)&WtT[rr][qb + 8];
            float4 q3 = *(const float4*)&WtT[rr][qb + 12];
            float4 q4 = *(const float4*)&WtT[rr][qb + 16];
            fma20(vv, q0, q1, q2, q3, q4, acc);
        }
    }
#undef K4_LOAD
#undef K4_VST
#undef SWZ
    int tp20 = (w >> 1) * 20;
    size_t obase = (size_t)(gb * 8 + m) * 75 * 256 + dlc;
#pragma unroll
    for (int j = 0; j < 20; ++j) {
        int t = tb + tp20 + j;
        if (t < 75)
            *(float2*)&VTP[obase + (size_t)t * 256] = acc[j];
    }
}

// K5: v_tidal = sum_m VTP; logit[gb][t] = <vt/||vt||, e/||e||>.
__global__ __launch_bounds__(256) void k5_logit(const float* __restrict__ text,
                                                float* __restrict__ ws) {
    __shared__ float red[256];
    const float* VTP = ws + OFF_S;
    float* LG = ws + OFF_LG;
    int blk = blockIdx.x;
    int t = blk % 75, gb = blk / 75, g = gb / 5;
    int tid = threadIdx.x;
    float vt = 0.f;
#pragma unroll
    for (int m = 0; m < 8; ++m)
        vt += VTP[((size_t)(gb * 8 + m) * 75 + t) * 256 + tid];
    int seg = t / 15, l = t % 15;
    float ev = text[((size_t)(g * 5 + seg) * 15 + l) * 256 + tid];
    float nvt = bredsum(vt * vt, red);
    float nev = bredsum(ev * ev, red);
    float dot = bredsum(vt * ev, red);
    if (tid == 0)
        LG[gb * 75 + t] = dot / (fmaxf(sqrtf(nvt), 1e-12f) * fmaxf(sqrtf(nev), 1e-12f));
}

// K6: vns[gb][m][d] = sum_hw v[hw][d]/max(||v[hw]||,1e-12)
__global__ __launch_bounds__(256) void k6_vns(const float* __restrict__ image,
                                              float* __restrict__ ws) {
    __shared__ float A[32][257];
    __shared__ float rn[256];
    __shared__ float ps[256];
    float* VNS = ws + OFF_VNS;
    int blk = blockIdx.x;
    int m = blk & 7, gb = blk >> 3;
    const float* cell = image + (size_t)(gb * 8 + m) * ND * NHW;
    int tid = threadIdx.x;
    float nsq = 0.f;
    for (int d = 0; d < 256; ++d) {
        float v = cell[d * 256 + tid];
        nsq += v * v;
    }
    rn[tid] = 1.f / fmaxf(sqrtf(nsq), 1e-12f);
    int d_loc = tid & 31, sub = tid >> 5; // 8 subs x 32 d
    for (int d0 = 0; d0 < 256; d0 += 32) {
        __syncthreads();
#pragma unroll
        for (int i = 0; i < 32; ++i) A[i][tid] = cell[(d0 + i) * 256 + tid];
        __syncthreads();
        float partial = 0.f;
#pragma unroll
        for (int k = 0; k < 32; ++k) {
            int hw = sub + 8 * k;
            partial += A[d_loc][hw] * rn[hw];
        }
        ps[tid] = partial; __syncthreads();
        if (tid < 128) ps[tid] += ps[tid + 128];
        __syncthreads();
        if (tid < 64) ps[tid] += ps[tid + 64];
        __syncthreads();
        if (tid < 32)
            VNS[((size_t)gb * 8 + m) * 256 + d0 + tid] = ps[tid] + ps[tid + 32];
    }
}

// K7: beta from SD; em[s][d] = sum_l beta*e; logit2[gb][m][s] = <em/||em||, vns>/256.
__global__ __launch_bounds__(256) void k7_em(const float* __restrict__ text,
                                             float* __restrict__ ws) {
    __shared__ float red[256];
    __shared__ float sdv[75];
    __shared__ float segs[5];
    __shared__ float betas[5][15];
    const float* SD = ws + OFF_SD;
    const float* VNS = ws + OFF_VNS;
    float* BETA = ws + OFF_BETA;
    float* LG2 = ws + OFF_LG2;
    int blk = blockIdx.x;
    int m = blk & 7, gb = blk >> 3, g = gb / 5;
    int tid = threadIdx.x;
    if (tid < 75) sdv[tid] = SD[((size_t)gb * 8 + m) * 75 + tid];
    __syncthreads();
    if (tid < 5) {
        float s = 0.f;
        for (int l = 0; l < 15; ++l) s += sdv[tid * 15 + l];
        segs[tid] = s;
    }
    __syncthreads();
    if (tid < 75) {
        float b = sdv[tid] / segs[tid / 15];
        betas[tid / 15][tid % 15] = b;
        BETA[((size_t)gb * 8 + m) * 75 + tid] = b;
    }
    __syncthreads();
    float vns = VNS[((size_t)gb * 8 + m) * 256 + tid];
    for (int s = 0; s < 5; ++s) {
        float em = 0.f;
#pragma unroll
        for (int l = 0; l < 15; ++l)
            em += betas[s][l] * text[((size_t)(g * 5 + s) * 15 + l) * 256 + tid];
        float nem = bredsum(em * em, red);
        float dot = bredsum(em * vns, red);
        if (tid == 0)
            LG2[((size_t)gb * 8 + m) * 5 + s] =
                dot / fmaxf(sqrtf(nem), 1e-12f) * (1.f / 256.f);
        __syncthreads();
    }
}

// K8: per-g block assembly -> BLK[g]
__global__ __launch_bounds__(256) void k8_final(float* __restrict__ ws) {
    __shared__ float lsm[5][5];
    __shared__ float offsq[5][64];
    __shared__ float regs[5];
    const float* LG = ws + OFF_LG;
    const float* LG2 = ws + OFF_LG2;
    const float* BETA = ws + OFF_BETA;
    float* BLK = ws + OFF_BLK;
    int g = blockIdx.x;
    int tid = threadIdx.x;
    if (tid < 25) {
        int b = tid / 5, s = tid % 5;
        int gb = g * 5 + b;
        float s1 = 0.f;
        for (int l = 0; l < 15; ++l) s1 += expf(LG[gb * 75 + s * 15 + l]);
        float s2 = 0.f;
        for (int mm = 0; mm < 8; ++mm) s2 += expf(LG2[((size_t)gb * 8 + mm) * 5 + s]);
        float l1 = logf(powf(s1, 0.2f) + 1e-10f);
        float l2 = logf(powf(s2, 0.2f) + 1e-10f);
        lsm[b][s] = 10.f * (l1 + l2);
    }
    for (int p = tid; p < 320; p += 256) {
        int b = p >> 6, mn = p & 63, mm = mn >> 3, nn = mn & 7;
        int gb = g * 5 + b;
        const float* bm = BETA + ((size_t)gb * 8 + mm) * 75;
        const float* bn = BETA + ((size_t)gb * 8 + nn) * 75;
        float acc = 0.f;
        for (int t2 = 0; t2 < 75; ++t2) acc += bm[t2] * bn[t2];
        offsq[b][mn] = (mm == nn) ? 0.f : acc * acc;
    }
    __syncthreads();
    if (tid < 5) {
        float s = 0.f;
        for (int i = 0; i < 64; ++i) s += offsq[tid][i];
        regs[tid] = sqrtf(s);
    }
    __syncthreads();
    if (tid == 0) {
        float loss_reg = 0.f;
        for (int b = 0; b < 5; ++b) loss_reg += regs[b];
        loss_reg *= 0.2f;
        float pdq = 0.f, pqd = 0.f;
        for (int i = 0; i < 5; ++i) {
            float rsum = 0.f, csum = 0.f;
            for (int j = 0; j < 5; ++j) { rsum += lsm[i][j]; csum += lsm[j][i]; }
            float di = lsm[i][i];
            pdq += -logf(di / rsum + 1e-10f);
            pqd += -logf(di / csum + 1e-10f);
        }
        BLK[g] = (pdq + pqd) * 0.2f + loss_reg;
    }
}

__global__ void k9_out(const float* __restrict__ ws, float* __restrict__ out) {
    if (threadIdx.x == 0) {
        float s = 0.f;
        for (int g2 = 0; g2 < 8; ++g2) s += ws[OFF_BLK + g2];
        out[0] = s / 9.f;
    }
}

extern "C" void kernel_launch(void* const* d_in, const int* in_sizes, int n_in,
                              void* d_out, int out_size, void* d_ws, size_t ws_size,
                              hipStream_t stream) {
    const float* image = (const float*)d_in[0];
    const float* text  = (const float*)d_in[1];
    float* ws = (float*)d_ws;
    float* out = (float*)d_out;
    hipLaunchKernelGGL(k1_gemm_s,   dim3(640),  dim3(256), 0, stream, image, text, ws);
    hipLaunchKernelGGL(k2_rowstats, dim3(320),  dim3(256), 0, stream, ws);
    hipLaunchKernelGGL(k3_colstats, dim3(3000), dim3(256), 0, stream, ws);
    hipLaunchKernelGGL(k4_vtidal,   dim3(640),  dim3(256), 0, stream, image, ws);
    hipLaunchKernelGGL(k5_logit,    dim3(3000), dim3(256), 0, stream, text, ws);
    hipLaunchKernelGGL(k6_vns,      dim3(320),  dim3(256), 0, stream, image, ws);
    hipLaunchKernelGGL(k7_em,       dim3(320),  dim3(256), 0, stream, text, ws);
    hipLaunchKernelGGL(k8_final,    dim3(8),    dim3(256), 0, stream, ws);
    hipLaunchKernelGGL(k9_out,      dim3(1),    dim3(64),  0, stream, ws, out);
}

// Round 2
// 640.254 us; speedup vs baseline: 2.6957x; 2.6957x over previous
//
#include <hip/hip_runtime.h>
#include <hip/hip_bf16.h>
#include <math.h>

// Shapes (fixed per reference): B=40, M=8, D=256, H=16x16 -> HW=256, L=15
// Blocks: 8 blocks of 5 samples. Per block: R = 2048 regions, T = 75 tokens.
#define NG 8
#define NB5 5
#define NM 8
#define NHW 256
#define NR 2048
#define ND 256
#define NL 15
#define NT 75
#define NGB 40

// workspace layout (in floats)
#define OFF_S    0                         // s [gb][t][r], aliased later as VTP [gb][m][t][d]
#define SZ_S     (NGB*NT*NR)               // 6,144,000
#define OFF_W    (OFF_S + SZ_S)            // alpha [gb][t][r]
#define OFF_RMAX (OFF_W + SZ_S)            // [gb][seg][r]
#define SZ_RST   (NGB*5*NR)                // 409,600
#define OFF_RSUM (OFF_RMAX + SZ_RST)
#define OFF_SD   (OFF_RSUM + SZ_RST)       // [gb][m][t]
#define SZ_SD    (NGB*NM*NT)
#define OFF_VNS  (OFF_SD + SZ_SD)          // [gb][m][d]
#define SZ_VNS   (NGB*NM*ND)
#define OFF_LG   (OFF_VNS + SZ_VNS)        // logit [gb][t]
#define SZ_LG    (NGB*NT)
#define OFF_LG2  (OFF_LG + SZ_LG)          // logit2 [gb][m][s]
#define SZ_LG2   (NGB*NM*5)
#define OFF_BETA (OFF_LG2 + SZ_LG2)        // [gb][m][t]
#define SZ_BETA  (NGB*NM*NT)
#define OFF_BLK  (OFF_BETA + SZ_BETA)      // [g]

__device__ __forceinline__ float bredsum(float v, float* red) {
    int tid = threadIdx.x;
    red[tid] = v; __syncthreads();
    for (int s2 = 128; s2 > 0; s2 >>= 1) {
        if (tid < s2) red[tid] += red[tid + s2];
        __syncthreads();
    }
    float r = red[0]; __syncthreads();
    return r;
}

// K1: s[gb][t][m*256+hw] = sum_d v[r][d]*e[t][d].
// Round-0 proven inner structure (float4 acc[10], named-register prefetch,
// 2 barriers/chunk). Reshaped to 128-thread (2-wave) blocks, grid 1280 =
// 4 t-groups x 320 cells = EXACTLY 5 blocks/CU (round-0's 640 = 2.5/CU had a
// ~1.2x tail). Chunk = 16 d-rows; LDS 18.4KB -> 8 blocks/CU capacity; each
// wave still owns 10 t (same LDS bytes/FMA, same d-accumulation order ->
// bit-identical output).
__global__ __launch_bounds__(128, 4) void k1_gemm_s(const float* __restrict__ image,
                                                    const float* __restrict__ text,
                                                    float* __restrict__ ws) {
    __shared__ __align__(16) float A[16][260];   // [dd][hw]
    __shared__ __align__(16) float Et[16][28];   // [dd][w*12 + j]
    float* Sg = ws + OFF_S;
    int blk = blockIdx.x;
    int tg = blk / 320;                    // 0..3, t-group
    int rest = blk - tg * 320;
    int m = rest & 7, gb = rest >> 3;
    int g = gb / 5;
    int tb = tg * 20;                      // block covers t in [tb, tb+20)
    const float* cell = image + (size_t)(gb * 8 + m) * ND * NHW; // [d][hw]
    const float* tbase = text + (size_t)g * 75 * 256;
    int tid = threadIdx.x;
    int lane = tid & 63;
    int w = __builtin_amdgcn_readfirstlane(tid >> 6); // 0..1; wave owns t = tb+w*10+j
    int hw4 = lane * 4;
    int arow = tid >> 6;          // 0..1, A-row base (dd = arow + 2*i)
    int acol = (tid & 63) * 4;    // A col (float4)
    int edd  = tid & 15;          // Et dd
    int etc0 = tid >> 4;          // 0..7; tcl = etc0 + 8*i
    // text staging: tc = etc0 + 8*I (I=0,1,2), valid tc<20
    int tc1 = etc0 + 8, tc2 = etc0 + 16;
    int te0 = tb + etc0;                         // <=67, always valid
    int te1 = tb + tc1; if (te1 > 74) te1 = 74;  // clamp (dup value)
    int te2 = tb + tc2; if (te2 > 74) te2 = 74;  // clamp (dup value)
    bool ev2 = etc0 < 4;                         // tc2 < 20
    int ec0 = etc0;                              // col map: tc + (tc>=10)*2
    int ec1 = tc1 + (tc1 >= 10 ? 2 : 0);
    int ec2 = tc2 + 2;
    float4 acc[10];
#pragma unroll
    for (int j = 0; j < 10; ++j) acc[j] = make_float4(0.f, 0.f, 0.f, 0.f);
    float4 p0, p1, p2, p3, p4, p5, p6, p7;
    float e0, e1, e2 = 0.f;
#define K1_LOAD(D0)                                                              \
    p0 = *(const float4*)&cell[(size_t)((D0) + arow +  0) * 256 + acol];         \
    p1 = *(const float4*)&cell[(size_t)((D0) + arow +  2) * 256 + acol];         \
    p2 = *(const float4*)&cell[(size_t)((D0) + arow +  4) * 256 + acol];         \
    p3 = *(const float4*)&cell[(size_t)((D0) + arow +  6) * 256 + acol];         \
    p4 = *(const float4*)&cell[(size_t)((D0) + arow +  8) * 256 + acol];         \
    p5 = *(const float4*)&cell[(size_t)((D0) + arow + 10) * 256 + acol];         \
    p6 = *(const float4*)&cell[(size_t)((D0) + arow + 12) * 256 + acol];         \
    p7 = *(const float4*)&cell[(size_t)((D0) + arow + 14) * 256 + acol];         \
    e0 = tbase[(size_t)te0 * 256 + (D0) + edd];                                  \
    e1 = tbase[(size_t)te1 * 256 + (D0) + edd];                                  \
    if (ev2) e2 = tbase[(size_t)te2 * 256 + (D0) + edd];
    K1_LOAD(0)
    for (int c = 0; c < 16; ++c) {
        __syncthreads();
        *(float4*)&A[arow +  0][acol] = p0;
        *(float4*)&A[arow +  2][acol] = p1;
        *(float4*)&A[arow +  4][acol] = p2;
        *(float4*)&A[arow +  6][acol] = p3;
        *(float4*)&A[arow +  8][acol] = p4;
        *(float4*)&A[arow + 10][acol] = p5;
        *(float4*)&A[arow + 12][acol] = p6;
        *(float4*)&A[arow + 14][acol] = p7;
        Et[edd][ec0] = e0;
        Et[edd][ec1] = e1;
        if (ev2) Et[edd][ec2] = e2;
        __syncthreads();
        if (c < 15) { K1_LOAD((c + 1) * 16) }
        for (int dd = 0; dd < 16; ++dd) {
            float4 av = *(const float4*)&A[dd][hw4];
            float4 q0 = *(const float4*)&Et[dd][w * 12];
            float4 q1 = *(const float4*)&Et[dd][w * 12 + 4];
            float2 q2 = *(const float2*)&Et[dd][w * 12 + 8];
            float ev[10] = {q0.x, q0.y, q0.z, q0.w, q1.x, q1.y, q1.z, q1.w, q2.x, q2.y};
#pragma unroll
            for (int j = 0; j < 10; ++j) {
                acc[j].x += av.x * ev[j]; acc[j].y += av.y * ev[j];
                acc[j].z += av.z * ev[j]; acc[j].w += av.w * ev[j];
            }
        }
    }
#undef K1_LOAD
#pragma unroll
    for (int j = 0; j < 10; ++j) {
        int t = tb + w * 10 + j;
        if (t < 75)
            *(float4*)&Sg[((size_t)gb * 75 + t) * 2048 + m * 256 + hw4] = acc[j];
    }
}

// K2: per-(r,seg) max/sumexp over the 15 tokens of the segment.
__global__ __launch_bounds__(256) void k2_rowstats(float* __restrict__ ws) {
    const float* Sg = ws + OFF_S;
    float* RMAX = ws + OFF_RMAX;
    float* RSUM = ws + OFF_RSUM;
    int blk = blockIdx.x;
    int m = blk & 7, gb = blk >> 3;
    int r = m * 256 + threadIdx.x;
    const float* base = Sg + (size_t)gb * 75 * 2048 + r;
    for (int seg = 0; seg < 5; ++seg) {
        float v[15]; float mx = -1e30f;
#pragma unroll
        for (int l = 0; l < 15; ++l) {
            v[l] = base[(size_t)(seg * 15 + l) * 2048];
            mx = fmaxf(mx, v[l]);
        }
        float sm = 0.f;
#pragma unroll
        for (int l = 0; l < 15; ++l) sm += __expf(v[l] - mx);
        RMAX[((size_t)gb * 5 + seg) * 2048 + r] = mx;
        RSUM[((size_t)gb * 5 + seg) * 2048 + r] = sm;
    }
}

// K3: per (gb,t) column over r=2048: colmax(s), colsum exp(s-cmax), colsum exp(s_nt);
// writes alpha (W) and per-m sums SD = sum_hw exp(p2). One pass over s.
__global__ __launch_bounds__(256) void k3_colstats(float* __restrict__ ws) {
    __shared__ float red[256];
    __shared__ float red8[8][256];
    const float* Sg = ws + OFF_S;
    const float* RMAX = ws + OFF_RMAX;
    const float* RSUM = ws + OFF_RSUM;
    float* W = ws + OFF_W;
    float* SD = ws + OFF_SD;
    int blk = blockIdx.x;           // t + 75*gb
    int t = blk % 75, gb = blk / 75;
    int seg = t / 15;
    int tid = threadIdx.x;
    const float* col = Sg + ((size_t)gb * 75 + t) * 2048;
    const float* rmx = RMAX + ((size_t)gb * 5 + seg) * 2048;
    const float* rsm = RSUM + ((size_t)gb * 5 + seg) * 2048;
    float sv[8], ent[8];
    float lmax = -1e30f, lsnt = 0.f;
#pragma unroll
    for (int k = 0; k < 8; ++k) {
        int r = tid + 256 * k;
        float s = col[r];
        sv[k] = s;
        float snt = 4.f * __expf(s - rmx[r]) / rsm[r];
        float e = __expf(snt);
        ent[k] = e;
        lsnt += e;
        lmax = fmaxf(lmax, s);
    }
    red[tid] = lmax; __syncthreads();
    for (int s2 = 128; s2 > 0; s2 >>= 1) {
        if (tid < s2) red[tid] = fmaxf(red[tid], red[tid + s2]);
        __syncthreads();
    }
    float cmax = red[0]; __syncthreads();
    float pe[8]; float lse = 0.f;
#pragma unroll
    for (int k = 0; k < 8; ++k) { pe[k] = __expf(sv[k] - cmax); lse += pe[k]; }
    float csum = bredsum(lse, red);
    float csnt = bredsum(lsnt, red);
    float inv = 1.f / csnt;
#pragma unroll
    for (int k = 0; k < 8; ++k)
        W[((size_t)gb * 75 + t) * 2048 + tid + 256 * k] = ent[k] * inv;
    float icsum = 1.f / csum;
#pragma unroll
    for (int k = 0; k < 8; ++k) red8[k][tid] = __expf(pe[k] * icsum);
    __syncthreads();
    for (int s2 = 128; s2 > 0; s2 >>= 1) {
        if (tid < s2) {
#pragma unroll
            for (int k2 = 0; k2 < 8; ++k2) red8[k2][tid] += red8[k2][tid + s2];
        }
        __syncthreads();
    }
    if (tid < 8) SD[((size_t)gb * 8 + tid) * 75 + t] = red8[tid][0];
}

// K4: v_tidal partials per m-cell: VTP[gb][m][t][d] = sum_{r in cell} alpha[r][t]*v[r][d].
// Round-0 proven structure, reshaped like k1: 128-thread blocks, grid 1280
// (4 t-groups x 320 cells = 5 blocks/CU, no tail), chunk = 16 rr rows.
// V-transpose scatter at 128 thr is 2-way bank aliasing (free).
__global__ __launch_bounds__(128, 4) void k4_vtidal(const float* __restrict__ image,
                                                    float* __restrict__ ws) {
    __shared__ __align__(16) float V[16][260];  // [rr][d]
    __shared__ __align__(16) float WtT[16][28]; // [rr][w*12 + j]
    const float* W = ws + OFF_W;
    float* VTP = ws + OFF_S; // s is dead; reuse
    int blk = blockIdx.x;
    int tg = blk / 320;
    int rest = blk - tg * 320;
    int m = rest & 7, gb = rest >> 3;
    int tb = tg * 20;
    const float* cell = image + (size_t)(gb * 8 + m) * ND * NHW; // [d][hw]
    int tid = threadIdx.x;
    int lane = tid & 63;
    int w = __builtin_amdgcn_readfirstlane(tid >> 6); // 0..1; wave owns t = tb+w*10+j
    int d4 = lane * 4;
    int rr4  = (tid & 3) * 4;     // V rr base for this thread's float4 (0,4,8,12)
    int drow = tid >> 2;          // 0..31; d = drow + 32*i
    int wrr  = tid & 15;          // WtT rr
    int wtc0 = tid >> 4;          // 0..7; tcl = wtc0 + 8*i
    float4 acc[10];
#pragma unroll
    for (int j = 0; j < 10; ++j) acc[j] = make_float4(0.f, 0.f, 0.f, 0.f);
    const float* wb = W + (size_t)gb * 75 * 2048 + m * 256;
    // alpha staging: tc = wtc0 + 8*I (I=0,1,2), valid tc<20
    int wtc1 = wtc0 + 8, wtc2 = wtc0 + 16;
    int tw0 = tb + wtc0;                          // <=67 valid
    int tw1 = tb + wtc1; if (tw1 > 74) tw1 = 74;  // clamp dup
    int tw2 = tb + wtc2; if (tw2 > 74) tw2 = 74;  // clamp dup
    bool wv2 = wtc0 < 4;                          // tc2 < 20
    int wc0 = wtc0;
    int wc1 = wtc1 + (wtc1 >= 10 ? 2 : 0);
    int wc2 = wtc2 + 2;
    float4 p0, p1, p2, p3, p4, p5, p6, p7;
    float w0, w1, w2 = 0.f;
#define K4_LOAD(RC)                                                               \
    p0 = *(const float4*)&cell[(size_t)(drow +   0) * 256 + (RC) * 16 + rr4];     \
    p1 = *(const float4*)&cell[(size_t)(drow +  32) * 256 + (RC) * 16 + rr4];     \
    p2 = *(const float4*)&cell[(size_t)(drow +  64) * 256 + (RC) * 16 + rr4];     \
    p3 = *(const float4*)&cell[(size_t)(drow +  96) * 256 + (RC) * 16 + rr4];     \
    p4 = *(const float4*)&cell[(size_t)(drow + 128) * 256 + (RC) * 16 + rr4];     \
    p5 = *(const float4*)&cell[(size_t)(drow + 160) * 256 + (RC) * 16 + rr4];     \
    p6 = *(const float4*)&cell[(size_t)(drow + 192) * 256 + (RC) * 16 + rr4];     \
    p7 = *(const float4*)&cell[(size_t)(drow + 224) * 256 + (RC) * 16 + rr4];     \
    w0 = wb[(size_t)tw0 * 2048 + (RC) * 16 + wrr];                                \
    w1 = wb[(size_t)tw1 * 2048 + (RC) * 16 + wrr];                                \
    if (wv2) w2 = wb[(size_t)tw2 * 2048 + (RC) * 16 + wrr];
#define K4_VST(P, DOFF)                                                           \
    V[rr4 + 0][drow + (DOFF)] = (P).x;                                            \
    V[rr4 + 1][drow + (DOFF)] = (P).y;                                            \
    V[rr4 + 2][drow + (DOFF)] = (P).z;                                            \
    V[rr4 + 3][drow + (DOFF)] = (P).w;
    K4_LOAD(0)
    for (int rc = 0; rc < 16; ++rc) {
        __syncthreads();
        K4_VST(p0,   0) K4_VST(p1,  32) K4_VST(p2,  64) K4_VST(p3,  96)
        K4_VST(p4, 128) K4_VST(p5, 160) K4_VST(p6, 192) K4_VST(p7, 224)
        WtT[wrr][wc0] = w0;
        WtT[wrr][wc1] = w1;
        if (wv2) WtT[wrr][wc2] = w2;
        __syncthreads();
        if (rc < 15) { K4_LOAD(rc + 1) }
        for (int rr = 0; rr < 16; ++rr) {
            float4 vv = *(const float4*)&V[rr][d4];
            float4 q0 = *(const float4*)&WtT[rr][w * 12];
            float4 q1 = *(const float4*)&WtT[rr][w * 12 + 4];
            float2 q2 = *(const float2*)&WtT[rr][w * 12 + 8];
            float wv[10] = {q0.x, q0.y, q0.z, q0.w, q1.x, q1.y, q1.z, q1.w, q2.x, q2.y};
#pragma unroll
            for (int j = 0; j < 10; ++j) {
                acc[j].x += vv.x * wv[j]; acc[j].y += vv.y * wv[j];
                acc[j].z += vv.z * wv[j]; acc[j].w += vv.w * wv[j];
            }
        }
    }
#undef K4_LOAD
#undef K4_VST
#pragma unroll
    for (int j = 0; j < 10; ++j) {
        int t = tb + w * 10 + j;
        if (t < 75)
            *(float4*)&VTP[((size_t)(gb * 8 + m) * 75 + t) * 256 + d4] = acc[j];
    }
}

// K5: v_tidal = sum_m VTP; logit[gb][t] = <vt/||vt||, e/||e||>.
__global__ __launch_bounds__(256) void k5_logit(const float* __restrict__ text,
                                                float* __restrict__ ws) {
    __shared__ float red[256];
    const float* VTP = ws + OFF_S;
    float* LG = ws + OFF_LG;
    int blk = blockIdx.x;
    int t = blk % 75, gb = blk / 75, g = gb / 5;
    int tid = threadIdx.x;
    float vt = 0.f;
#pragma unroll
    for (int m = 0; m < 8; ++m)
        vt += VTP[((size_t)(gb * 8 + m) * 75 + t) * 256 + tid];
    int seg = t / 15, l = t % 15;
    float ev = text[((size_t)(g * 5 + seg) * 15 + l) * 256 + tid];
    float nvt = bredsum(vt * vt, red);
    float nev = bredsum(ev * ev, red);
    float dot = bredsum(vt * ev, red);
    if (tid == 0)
        LG[gb * 75 + t] = dot / (fmaxf(sqrtf(nvt), 1e-12f) * fmaxf(sqrtf(nev), 1e-12f));
}

// K6: vns[gb][m][d] = sum_hw v[hw][d]/max(||v[hw]||,1e-12)
__global__ __launch_bounds__(256) void k6_vns(const float* __restrict__ image,
                                              float* __restrict__ ws) {
    __shared__ float A[32][257];
    __shared__ float rn[256];
    __shared__ float ps[256];
    float* VNS = ws + OFF_VNS;
    int blk = blockIdx.x;
    int m = blk & 7, gb = blk >> 3;
    const float* cell = image + (size_t)(gb * 8 + m) * ND * NHW;
    int tid = threadIdx.x;
    float nsq = 0.f;
    for (int d = 0; d < 256; ++d) {
        float v = cell[d * 256 + tid];
        nsq += v * v;
    }
    rn[tid] = 1.f / fmaxf(sqrtf(nsq), 1e-12f);
    int d_loc = tid & 31, sub = tid >> 5; // 8 subs x 32 d
    for (int d0 = 0; d0 < 256; d0 += 32) {
        __syncthreads();
#pragma unroll
        for (int i = 0; i < 32; ++i) A[i][tid] = cell[(d0 + i) * 256 + tid];
        __syncthreads();
        float partial = 0.f;
#pragma unroll
        for (int k = 0; k < 32; ++k) {
            int hw = sub + 8 * k;
            partial += A[d_loc][hw] * rn[hw];
        }
        ps[tid] = partial; __syncthreads();
        if (tid < 128) ps[tid] += ps[tid + 128];
        __syncthreads();
        if (tid < 64) ps[tid] += ps[tid + 64];
        __syncthreads();
        if (tid < 32)
            VNS[((size_t)gb * 8 + m) * 256 + d0 + tid] = ps[tid] + ps[tid + 32];
    }
}

// K7: beta from SD; em[s][d] = sum_l beta*e; logit2[gb][m][s] = <em/||em||, vns>/256.
__global__ __launch_bounds__(256) void k7_em(const float* __restrict__ text,
                                             float* __restrict__ ws) {
    __shared__ float red[256];
    __shared__ float sdv[75];
    __shared__ float segs[5];
    __shared__ float betas[5][15];
    const float* SD = ws + OFF_SD;
    const float* VNS = ws + OFF_VNS;
    float* BETA = ws + OFF_BETA;
    float* LG2 = ws + OFF_LG2;
    int blk = blockIdx.x;
    int m = blk & 7, gb = blk >> 3, g = gb / 5;
    int tid = threadIdx.x;
    if (tid < 75) sdv[tid] = SD[((size_t)gb * 8 + m) * 75 + tid];
    __syncthreads();
    if (tid < 5) {
        float s = 0.f;
        for (int l = 0; l < 15; ++l) s += sdv[tid * 15 + l];
        segs[tid] = s;
    }
    __syncthreads();
    if (tid < 75) {
        float b = sdv[tid] / segs[tid / 15];
        betas[tid / 15][tid % 15] = b;
        BETA[((size_t)gb * 8 + m) * 75 + tid] = b;
    }
    __syncthreads();
    float vns = VNS[((size_t)gb * 8 + m) * 256 + tid];
    for (int s = 0; s < 5; ++s) {
        float em = 0.f;
#pragma unroll
        for (int l = 0; l < 15; ++l)
            em += betas[s][l] * text[((size_t)(g * 5 + s) * 15 + l) * 256 + tid];
        float nem = bredsum(em * em, red);
        float dot = bredsum(em * vns, red);
        if (tid == 0)
            LG2[((size_t)gb * 8 + m) * 5 + s] =
                dot / fmaxf(sqrtf(nem), 1e-12f) * (1.f / 256.f);
        __syncthreads();
    }
}

// K8: per-g block assembly -> BLK[g]
__global__ __launch_bounds__(256) void k8_final(float* __restrict__ ws) {
    __shared__ float lsm[5][5];
    __shared__ float offsq[5][64];
    __shared__ float regs[5];
    const float* LG = ws + OFF_LG;
    const float* LG2 = ws + OFF_LG2;
    const float* BETA = ws + OFF_BETA;
    float* BLK = ws + OFF_BLK;
    int g = blockIdx.x;
    int tid = threadIdx.x;
    if (tid < 25) {
        int b = tid / 5, s = tid % 5;
        int gb = g * 5 + b;
        float s1 = 0.f;
        for (int l = 0; l < 15; ++l) s1 += expf(LG[gb * 75 + s * 15 + l]);
        float s2 = 0.f;
        for (int mm = 0; mm < 8; ++mm) s2 += expf(LG2[((size_t)gb * 8 + mm) * 5 + s]);
        float l1 = logf(powf(s1, 0.2f) + 1e-10f);
        float l2 = logf(powf(s2, 0.2f) + 1e-10f);
        lsm[b][s] = 10.f * (l1 + l2);
    }
    for (int p = tid; p < 320; p += 256) {
        int b = p >> 6, mn = p & 63, mm = mn >> 3, nn = mn & 7;
        int gb = g * 5 + b;
        const float* bm = BETA + ((size_t)gb * 8 + mm) * 75;
        const float* bn = BETA + ((size_t)gb * 8 + nn) * 75;
        float acc = 0.f;
        for (int t2 = 0; t2 < 75; ++t2) acc += bm[t2] * bn[t2];
        offsq[b][mn] = (mm == nn) ? 0.f : acc * acc;
    }
    __syncthreads();
    if (tid < 5) {
        float s = 0.f;
        for (int i = 0; i < 64; ++i) s += offsq[tid][i];
        regs[tid] = sqrtf(s);
    }
    __syncthreads();
    if (tid == 0) {
        float loss_reg = 0.f;
        for (int b = 0; b < 5; ++b) loss_reg += regs[b];
        loss_reg *= 0.2f;
        float pdq = 0.f, pqd = 0.f;
        for (int i = 0; i < 5; ++i) {
            float rsum = 0.f, csum = 0.f;
            for (int j = 0; j < 5; ++j) { rsum += lsm[i][j]; csum += lsm[j][i]; }
            float di = lsm[i][i];
            pdq += -logf(di / rsum + 1e-10f);
            pqd += -logf(di / csum + 1e-10f);
        }
        BLK[g] = (pdq + pqd) * 0.2f + loss_reg;
    }
}

__global__ void k9_out(const float* __restrict__ ws, float* __restrict__ out) {
    if (threadIdx.x == 0) {
        float s = 0.f;
        for (int g2 = 0; g2 < 8; ++g2) s += ws[OFF_BLK + g2];
        out[0] = s / 9.f;
    }
}

extern "C" void kernel_launch(void* const* d_in, const int* in_sizes, int n_in,
                              void* d_out, int out_size, void* d_ws, size_t ws_size,
                              hipStream_t stream) {
    const float* image = (const float*)d_in[0];
    const float* text  = (const float*)d_in[1];
    float* ws = (float*)d_ws;
    float* out = (float*)d_out;
    hipLaunchKernelGGL(k1_gemm_s,   dim3(1280), dim3(128), 0, stream, image, text, ws);
    hipLaunchKernelGGL(k2_rowstats, dim3(320),  dim3(256), 0, stream, ws);
    hipLaunchKernelGGL(k3_colstats, dim3(3000), dim3(256), 0, stream, ws);
    hipLaunchKernelGGL(k4_vtidal,   dim3(1280), dim3(128), 0, stream, image, ws);
    hipLaunchKernelGGL(k5_logit,    dim3(3000), dim3(256), 0, stream, text, ws);
    hipLaunchKernelGGL(k6_vns,      dim3(320),  dim3(256), 0, stream, image, ws);
    hipLaunchKernelGGL(k7_em,       dim3(320),  dim3(256), 0, stream, text, ws);
    hipLaunchKernelGGL(k8_final,    dim3(8),    dim3(256), 0, stream, ws);
    hipLaunchKernelGGL(k9_out,      dim3(1),    dim3(64),  0, stream, ws, out);
}

// Round 3
// 300.366 us; speedup vs baseline: 5.7460x; 2.1316x over previous
//
#include <hip/hip_runtime.h>
#include <hip/hip_bf16.h>
#include <math.h>

// Shapes (fixed per reference): B=40, M=8, D=256, H=16x16 -> HW=256, L=15
// Blocks: 8 blocks of 5 samples. Per block: R = 2048 regions, T = 75 tokens.
#define NG 8
#define NB5 5
#define NM 8
#define NHW 256
#define NR 2048
#define ND 256
#define NL 15
#define NT 75
#define NGB 40

// workspace layout (in floats)
#define OFF_S    0                         // s [gb][t][r], aliased later as VTP [gb][m][t][d]
#define SZ_S     (NGB*NT*NR)               // 6,144,000
#define OFF_W    (OFF_S + SZ_S)            // alpha [gb][t][r]
#define OFF_RMAX (OFF_W + SZ_S)            // [gb][seg][r]
#define SZ_RST   (NGB*5*NR)                // 409,600
#define OFF_RSUM (OFF_RMAX + SZ_RST)
#define OFF_SD   (OFF_RSUM + SZ_RST)       // [gb][m][t]
#define SZ_SD    (NGB*NM*NT)
#define OFF_VNS  (OFF_SD + SZ_SD)          // [gb][m][d]
#define SZ_VNS   (NGB*NM*ND)
#define OFF_LG   (OFF_VNS + SZ_VNS)        // logit [gb][t]
#define SZ_LG    (NGB*NT)
#define OFF_LG2  (OFF_LG + SZ_LG)          // logit2 [gb][m][s]
#define SZ_LG2   (NGB*NM*5)
#define OFF_BETA (OFF_LG2 + SZ_LG2)        // [gb][m][t]
#define SZ_BETA  (NGB*NM*NT)
#define OFF_BLK  (OFF_BETA + SZ_BETA)      // [g]

__device__ __forceinline__ float bredsum(float v, float* red) {
    int tid = threadIdx.x;
    red[tid] = v; __syncthreads();
    for (int s2 = 128; s2 > 0; s2 >>= 1) {
        if (tid < s2) red[tid] += red[tid + s2];
        __syncthreads();
    }
    float r = red[0]; __syncthreads();
    return r;
}

// K1: s[gb][t][m*256+hw] = sum_d v[r][d]*e[t][d].
// LDS-FREE version. Round-0's LDS variant was LDS-pipe-bound (4 waves
// redundantly re-reading the A-tile: ~45-60us of LDS pipe vs 21us VALU floor).
// Here the A-row read cell[dd*256+hw4] is a coalesced global_load_dwordx4
// streamed through L1/L2 (640MB L2 traffic total ~19us), and e[t][dd..dd+3]
// is WAVE-UNIFORM (t from readfirstlane, dd loop-uniform) -> s_load_dwordx4
// through the scalar cache, feeding v_fmac as the one legal scalar operand.
// No barriers, no staging; 4-deep named float4 prefetch covers L2 latency
// (guarded at the tail: last cell must not read past image end).
// dd accumulation order 0..255 sequential == round-0 -> bit-identical.
// launch_bounds (256,2): the ONLY proven-safe variant on this kernel
// (rounds 1/2: min-waves>=3 made the allocator clamp to an occupancy tier
// below register demand and spill the K-loop prefetch: 470MB scratch writes).
__global__ __launch_bounds__(256, 2) void k1_gemm_s(const float* __restrict__ image,
                                                    const float* __restrict__ text,
                                                    float* __restrict__ ws) {
    float* Sg = ws + OFF_S;
    int blk = blockIdx.x;
    int th = blk >= 320 ? 1 : 0;
    int rest = blk - th * 320;
    int m = rest & 7, gb = rest >> 3;
    int g = gb / 5;
    int tb = th * 40;                      // block covers t in [tb, tb+40)
    const float* cell = image + (size_t)(gb * 8 + m) * ND * NHW; // [d][hw]
    const float* tbase = text + (size_t)g * 75 * 256;
    int tid = threadIdx.x;
    int lane = tid & 63;
    int w = __builtin_amdgcn_readfirstlane(tid >> 6); // 0..3; wave owns t = tb+w*10+j
    int hw4 = lane * 4;
    int t0 = tb + w * 10;
    int tt[10];
#pragma unroll
    for (int j = 0; j < 10; ++j) { int t = t0 + j; tt[j] = t > 74 ? 74 : t; }
    float4 acc[10];
#pragma unroll
    for (int j = 0; j < 10; ++j) acc[j] = make_float4(0.f, 0.f, 0.f, 0.f);
#define K1_LD(DD) (*(const float4*)&cell[(size_t)(DD) * 256 + hw4])
    float4 a0 = K1_LD(0), a1 = K1_LD(1), a2 = K1_LD(2), a3 = K1_LD(3);
    for (int c = 0; c < 64; ++c) {
        int dd = c * 4;
        float4 n0, n1, n2, n3;
        if (c < 63) {
            n0 = K1_LD(dd + 4); n1 = K1_LD(dd + 5);
            n2 = K1_LD(dd + 6); n3 = K1_LD(dd + 7);
        }
        float4 e4[10];  // wave-uniform -> scalar loads
#pragma unroll
        for (int j = 0; j < 10; ++j)
            e4[j] = *(const float4*)&tbase[(size_t)tt[j] * 256 + dd];
#pragma unroll
        for (int j = 0; j < 10; ++j) {
            acc[j].x += a0.x * e4[j].x; acc[j].y += a0.y * e4[j].x;
            acc[j].z += a0.z * e4[j].x; acc[j].w += a0.w * e4[j].x;
        }
#pragma unroll
        for (int j = 0; j < 10; ++j) {
            acc[j].x += a1.x * e4[j].y; acc[j].y += a1.y * e4[j].y;
            acc[j].z += a1.z * e4[j].y; acc[j].w += a1.w * e4[j].y;
        }
#pragma unroll
        for (int j = 0; j < 10; ++j) {
            acc[j].x += a2.x * e4[j].z; acc[j].y += a2.y * e4[j].z;
            acc[j].z += a2.z * e4[j].z; acc[j].w += a2.w * e4[j].z;
        }
#pragma unroll
        for (int j = 0; j < 10; ++j) {
            acc[j].x += a3.x * e4[j].w; acc[j].y += a3.y * e4[j].w;
            acc[j].z += a3.z * e4[j].w; acc[j].w += a3.w * e4[j].w;
        }
        if (c < 63) { a0 = n0; a1 = n1; a2 = n2; a3 = n3; }
    }
#undef K1_LD
#pragma unroll
    for (int j = 0; j < 10; ++j) {
        int t = t0 + j;
        if (t < 75)
            *(float4*)&Sg[((size_t)gb * 75 + t) * 2048 + m * 256 + hw4] = acc[j];
    }
}

// K2: per-(r,seg) max/sumexp over the 15 tokens of the segment.
__global__ __launch_bounds__(256) void k2_rowstats(float* __restrict__ ws) {
    const float* Sg = ws + OFF_S;
    float* RMAX = ws + OFF_RMAX;
    float* RSUM = ws + OFF_RSUM;
    int blk = blockIdx.x;
    int m = blk & 7, gb = blk >> 3;
    int r = m * 256 + threadIdx.x;
    const float* base = Sg + (size_t)gb * 75 * 2048 + r;
    for (int seg = 0; seg < 5; ++seg) {
        float v[15]; float mx = -1e30f;
#pragma unroll
        for (int l = 0; l < 15; ++l) {
            v[l] = base[(size_t)(seg * 15 + l) * 2048];
            mx = fmaxf(mx, v[l]);
        }
        float sm = 0.f;
#pragma unroll
        for (int l = 0; l < 15; ++l) sm += __expf(v[l] - mx);
        RMAX[((size_t)gb * 5 + seg) * 2048 + r] = mx;
        RSUM[((size_t)gb * 5 + seg) * 2048 + r] = sm;
    }
}

// K3: per (gb,t) column over r=2048: colmax(s), colsum exp(s-cmax), colsum exp(s_nt);
// writes alpha (W) and per-m sums SD = sum_hw exp(p2). One pass over s.
__global__ __launch_bounds__(256) void k3_colstats(float* __restrict__ ws) {
    __shared__ float red[256];
    __shared__ float red8[8][256];
    const float* Sg = ws + OFF_S;
    const float* RMAX = ws + OFF_RMAX;
    const float* RSUM = ws + OFF_RSUM;
    float* W = ws + OFF_W;
    float* SD = ws + OFF_SD;
    int blk = blockIdx.x;           // t + 75*gb
    int t = blk % 75, gb = blk / 75;
    int seg = t / 15;
    int tid = threadIdx.x;
    const float* col = Sg + ((size_t)gb * 75 + t) * 2048;
    const float* rmx = RMAX + ((size_t)gb * 5 + seg) * 2048;
    const float* rsm = RSUM + ((size_t)gb * 5 + seg) * 2048;
    float sv[8], ent[8];
    float lmax = -1e30f, lsnt = 0.f;
#pragma unroll
    for (int k = 0; k < 8; ++k) {
        int r = tid + 256 * k;
        float s = col[r];
        sv[k] = s;
        float snt = 4.f * __expf(s - rmx[r]) / rsm[r];
        float e = __expf(snt);
        ent[k] = e;
        lsnt += e;
        lmax = fmaxf(lmax, s);
    }
    red[tid] = lmax; __syncthreads();
    for (int s2 = 128; s2 > 0; s2 >>= 1) {
        if (tid < s2) red[tid] = fmaxf(red[tid], red[tid + s2]);
        __syncthreads();
    }
    float cmax = red[0]; __syncthreads();
    float pe[8]; float lse = 0.f;
#pragma unroll
    for (int k = 0; k < 8; ++k) { pe[k] = __expf(sv[k] - cmax); lse += pe[k]; }
    float csum = bredsum(lse, red);
    float csnt = bredsum(lsnt, red);
    float inv = 1.f / csnt;
#pragma unroll
    for (int k = 0; k < 8; ++k)
        W[((size_t)gb * 75 + t) * 2048 + tid + 256 * k] = ent[k] * inv;
    float icsum = 1.f / csum;
#pragma unroll
    for (int k = 0; k < 8; ++k) red8[k][tid] = __expf(pe[k] * icsum);
    __syncthreads();
    for (int s2 = 128; s2 > 0; s2 >>= 1) {
        if (tid < s2) {
#pragma unroll
            for (int k2 = 0; k2 < 8; ++k2) red8[k2][tid] += red8[k2][tid + s2];
        }
        __syncthreads();
    }
    if (tid < 8) SD[((size_t)gb * 8 + tid) * 75 + t] = red8[tid][0];
}

// K4: v_tidal partials per m-cell: VTP[gb][m][t][d] = sum_{r in cell} alpha[r][t]*v[r][d].
// Round-0 PROVEN version, verbatim (65us, VGPR 72, no spill). Needs LDS for
// the V transpose (direct global reads would be a 64-line gather per instr).
__global__ __launch_bounds__(256, 2) void k4_vtidal(const float* __restrict__ image,
                                                    float* __restrict__ ws) {
    __shared__ __align__(16) float V[32][260];  // [rr][d]
    __shared__ __align__(16) float WtT[32][52]; // [rr][w*12 + j]
    const float* W = ws + OFF_W;
    float* VTP = ws + OFF_S; // s is dead; reuse
    int blk = blockIdx.x;
    int th = blk >= 320 ? 1 : 0;
    int rest = blk - th * 320;
    int m = rest & 7, gb = rest >> 3;
    int tb = th * 40;
    const float* cell = image + (size_t)(gb * 8 + m) * ND * NHW; // [d][hw]
    int tid = threadIdx.x;
    int lane = tid & 63;
    int w = __builtin_amdgcn_readfirstlane(tid >> 6); // 0..3; wave owns t = tb+w*10+j
    int d4 = lane * 4;
    int rr4  = (tid & 7) * 4;     // V rr base for this thread's float4
    int drow = tid >> 3;          // d = drow + 32*i
    int wrr  = tid & 31;          // WtT rr
    int wtc0 = tid >> 5;          // tcl = wtc0 + 8*i
    float4 acc[10];
#pragma unroll
    for (int j = 0; j < 10; ++j) acc[j] = make_float4(0.f, 0.f, 0.f, 0.f);
    const float* wb = W + (size_t)gb * 75 * 2048 + m * 256;
    float4 p0, p1, p2, p3, p4, p5, p6, p7;
    float w0, w1, w2, w3, w4;
#define K4_T(I) ((tb + wtc0 + 8 * (I)) > 74 ? 74 : (tb + wtc0 + 8 * (I)))
#define K4_LOAD(RC)                                                               \
    p0 = *(const float4*)&cell[(size_t)(drow +   0) * 256 + (RC) * 32 + rr4];     \
    p1 = *(const float4*)&cell[(size_t)(drow +  32) * 256 + (RC) * 32 + rr4];     \
    p2 = *(const float4*)&cell[(size_t)(drow +  64) * 256 + (RC) * 32 + rr4];     \
    p3 = *(const float4*)&cell[(size_t)(drow +  96) * 256 + (RC) * 32 + rr4];     \
    p4 = *(const float4*)&cell[(size_t)(drow + 128) * 256 + (RC) * 32 + rr4];     \
    p5 = *(const float4*)&cell[(size_t)(drow + 160) * 256 + (RC) * 32 + rr4];     \
    p6 = *(const float4*)&cell[(size_t)(drow + 192) * 256 + (RC) * 32 + rr4];     \
    p7 = *(const float4*)&cell[(size_t)(drow + 224) * 256 + (RC) * 32 + rr4];     \
    w0 = wb[(size_t)K4_T(0) * 2048 + (RC) * 32 + wrr];                            \
    w1 = wb[(size_t)K4_T(1) * 2048 + (RC) * 32 + wrr];                            \
    w2 = wb[(size_t)K4_T(2) * 2048 + (RC) * 32 + wrr];                            \
    w3 = wb[(size_t)K4_T(3) * 2048 + (RC) * 32 + wrr];                            \
    w4 = wb[(size_t)K4_T(4) * 2048 + (RC) * 32 + wrr];
#define K4_WCOL(I) (((wtc0 + 8 * (I)) / 10) * 12 + ((wtc0 + 8 * (I)) % 10))
#define K4_VST(P, DOFF)                                                           \
    V[rr4 + 0][drow + (DOFF)] = (P).x;                                            \
    V[rr4 + 1][drow + (DOFF)] = (P).y;                                            \
    V[rr4 + 2][drow + (DOFF)] = (P).z;                                            \
    V[rr4 + 3][drow + (DOFF)] = (P).w;
    K4_LOAD(0)
    for (int rc = 0; rc < 8; ++rc) {
        __syncthreads();
        K4_VST(p0,   0) K4_VST(p1,  32) K4_VST(p2,  64) K4_VST(p3,  96)
        K4_VST(p4, 128) K4_VST(p5, 160) K4_VST(p6, 192) K4_VST(p7, 224)
        WtT[wrr][K4_WCOL(0)] = w0;
        WtT[wrr][K4_WCOL(1)] = w1;
        WtT[wrr][K4_WCOL(2)] = w2;
        WtT[wrr][K4_WCOL(3)] = w3;
        WtT[wrr][K4_WCOL(4)] = w4;
        __syncthreads();
        if (rc < 7) { K4_LOAD(rc + 1) }
        for (int rr = 0; rr < 32; ++rr) {
            float4 vv = *(const float4*)&V[rr][d4];
            float4 q0 = *(const float4*)&WtT[rr][w * 12];
            float4 q1 = *(const float4*)&WtT[rr][w * 12 + 4];
            float2 q2 = *(const float2*)&WtT[rr][w * 12 + 8];
            float wv[10] = {q0.x, q0.y, q0.z, q0.w, q1.x, q1.y, q1.z, q1.w, q2.x, q2.y};
#pragma unroll
            for (int j = 0; j < 10; ++j) {
                acc[j].x += vv.x * wv[j]; acc[j].y += vv.y * wv[j];
                acc[j].z += vv.z * wv[j]; acc[j].w += vv.w * wv[j];
            }
        }
    }
#undef K4_LOAD
#undef K4_T
#undef K4_WCOL
#undef K4_VST
#pragma unroll
    for (int j = 0; j < 10; ++j) {
        int t = tb + w * 10 + j;
        if (t < 75)
            *(float4*)&VTP[((size_t)(gb * 8 + m) * 75 + t) * 256 + d4] = acc[j];
    }
}

// K5: v_tidal = sum_m VTP; logit[gb][t] = <vt/||vt||, e/||e||>.
__global__ __launch_bounds__(256) void k5_logit(const float* __restrict__ text,
                                                float* __restrict__ ws) {
    __shared__ float red[256];
    const float* VTP = ws + OFF_S;
    float* LG = ws + OFF_LG;
    int blk = blockIdx.x;
    int t = blk % 75, gb = blk / 75, g = gb / 5;
    int tid = threadIdx.x;
    float vt = 0.f;
#pragma unroll
    for (int m = 0; m < 8; ++m)
        vt += VTP[((size_t)(gb * 8 + m) * 75 + t) * 256 + tid];
    int seg = t / 15, l = t % 15;
    float ev = text[((size_t)(g * 5 + seg) * 15 + l) * 256 + tid];
    float nvt = bredsum(vt * vt, red);
    float nev = bredsum(ev * ev, red);
    float dot = bredsum(vt * ev, red);
    if (tid == 0)
        LG[gb * 75 + t] = dot / (fmaxf(sqrtf(nvt), 1e-12f) * fmaxf(sqrtf(nev), 1e-12f));
}

// K6: vns[gb][m][d] = sum_hw v[hw][d]/max(||v[hw]||,1e-12)
__global__ __launch_bounds__(256) void k6_vns(const float* __restrict__ image,
                                              float* __restrict__ ws) {
    __shared__ float A[32][257];
    __shared__ float rn[256];
    __shared__ float ps[256];
    float* VNS = ws + OFF_VNS;
    int blk = blockIdx.x;
    int m = blk & 7, gb = blk >> 3;
    const float* cell = image + (size_t)(gb * 8 + m) * ND * NHW;
    int tid = threadIdx.x;
    float nsq = 0.f;
    for (int d = 0; d < 256; ++d) {
        float v = cell[d * 256 + tid];
        nsq += v * v;
    }
    rn[tid] = 1.f / fmaxf(sqrtf(nsq), 1e-12f);
    int d_loc = tid & 31, sub = tid >> 5; // 8 subs x 32 d
    for (int d0 = 0; d0 < 256; d0 += 32) {
        __syncthreads();
#pragma unroll
        for (int i = 0; i < 32; ++i) A[i][tid] = cell[(d0 + i) * 256 + tid];
        __syncthreads();
        float partial = 0.f;
#pragma unroll
        for (int k = 0; k < 32; ++k) {
            int hw = sub + 8 * k;
            partial += A[d_loc][hw] * rn[hw];
        }
        ps[tid] = partial; __syncthreads();
        if (tid < 128) ps[tid] += ps[tid + 128];
        __syncthreads();
        if (tid < 64) ps[tid] += ps[tid + 64];
        __syncthreads();
        if (tid < 32)
            VNS[((size_t)gb * 8 + m) * 256 + d0 + tid] = ps[tid] + ps[tid + 32];
    }
}

// K7: beta from SD; em[s][d] = sum_l beta*e; logit2[gb][m][s] = <em/||em||, vns>/256.
__global__ __launch_bounds__(256) void k7_em(const float* __restrict__ text,
                                             float* __restrict__ ws) {
    __shared__ float red[256];
    __shared__ float sdv[75];
    __shared__ float segs[5];
    __shared__ float betas[5][15];
    const float* SD = ws + OFF_SD;
    const float* VNS = ws + OFF_VNS;
    float* BETA = ws + OFF_BETA;
    float* LG2 = ws + OFF_LG2;
    int blk = blockIdx.x;
    int m = blk & 7, gb = blk >> 3, g = gb / 5;
    int tid = threadIdx.x;
    if (tid < 75) sdv[tid] = SD[((size_t)gb * 8 + m) * 75 + tid];
    __syncthreads();
    if (tid < 5) {
        float s = 0.f;
        for (int l = 0; l < 15; ++l) s += sdv[tid * 15 + l];
        segs[tid] = s;
    }
    __syncthreads();
    if (tid < 75) {
        float b = sdv[tid] / segs[tid / 15];
        betas[tid / 15][tid % 15] = b;
        BETA[((size_t)gb * 8 + m) * 75 + tid] = b;
    }
    __syncthreads();
    float vns = VNS[((size_t)gb * 8 + m) * 256 + tid];
    for (int s = 0; s < 5; ++s) {
        float em = 0.f;
#pragma unroll
        for (int l = 0; l < 15; ++l)
            em += betas[s][l] * text[((size_t)(g * 5 + s) * 15 + l) * 256 + tid];
        float nem = bredsum(em * em, red);
        float dot = bredsum(em * vns, red);
        if (tid == 0)
            LG2[((size_t)gb * 8 + m) * 5 + s] =
                dot / fmaxf(sqrtf(nem), 1e-12f) * (1.f / 256.f);
        __syncthreads();
    }
}

// K8: per-g block assembly -> BLK[g]
__global__ __launch_bounds__(256) void k8_final(float* __restrict__ ws) {
    __shared__ float lsm[5][5];
    __shared__ float offsq[5][64];
    __shared__ float regs[5];
    const float* LG = ws + OFF_LG;
    const float* LG2 = ws + OFF_LG2;
    const float* BETA = ws + OFF_BETA;
    float* BLK = ws + OFF_BLK;
    int g = blockIdx.x;
    int tid = threadIdx.x;
    if (tid < 25) {
        int b = tid / 5, s = tid % 5;
        int gb = g * 5 + b;
        float s1 = 0.f;
        for (int l = 0; l < 15; ++l) s1 += expf(LG[gb * 75 + s * 15 + l]);
        float s2 = 0.f;
        for (int mm = 0; mm < 8; ++mm) s2 += expf(LG2[((size_t)gb * 8 + mm) * 5 + s]);
        float l1 = logf(powf(s1, 0.2f) + 1e-10f);
        float l2 = logf(powf(s2, 0.2f) + 1e-10f);
        lsm[b][s] = 10.f * (l1 + l2);
    }
    for (int p = tid; p < 320; p += 256) {
        int b = p >> 6, mn = p & 63, mm = mn >> 3, nn = mn & 7;
        int gb = g * 5 + b;
        const float* bm = BETA + ((size_t)gb * 8 + mm) * 75;
        const float* bn = BETA + ((size_t)gb * 8 + nn) * 75;
        float acc = 0.f;
        for (int t2 = 0; t2 < 75; ++t2) acc += bm[t2] * bn[t2];
        offsq[b][mn] = (mm == nn) ? 0.f : acc * acc;
    }
    __syncthreads();
    if (tid < 5) {
        float s = 0.f;
        for (int i = 0; i < 64; ++i) s += offsq[tid][i];
        regs[tid] = sqrtf(s);
    }
    __syncthreads();
    if (tid == 0) {
        float loss_reg = 0.f;
        for (int b = 0; b < 5; ++b) loss_reg += regs[b];
        loss_reg *= 0.2f;
        float pdq = 0.f, pqd = 0.f;
        for (int i = 0; i < 5; ++i) {
            float rsum = 0.f, csum = 0.f;
            for (int j = 0; j < 5; ++j) { rsum += lsm[i][j]; csum += lsm[j][i]; }
            float di = lsm[i][i];
            pdq += -logf(di / rsum + 1e-10f);
            pqd += -logf(di / csum + 1e-10f);
        }
        BLK[g] = (pdq + pqd) * 0.2f + loss_reg;
    }
}

__global__ void k9_out(const float* __restrict__ ws, float* __restrict__ out) {
    if (threadIdx.x == 0) {
        float s = 0.f;
        for (int g2 = 0; g2 < 8; ++g2) s += ws[OFF_BLK + g2];
        out[0] = s / 9.f;
    }
}

extern "C" void kernel_launch(void* const* d_in, const int* in_sizes, int n_in,
                              void* d_out, int out_size, void* d_ws, size_t ws_size,
                              hipStream_t stream) {
    const float* image = (const float*)d_in[0];
    const float* text  = (const float*)d_in[1];
    float* ws = (float*)d_ws;
    float* out = (float*)d_out;
    hipLaunchKernelGGL(k1_gemm_s,   dim3(640),  dim3(256), 0, stream, image, text, ws);
    hipLaunchKernelGGL(k2_rowstats, dim3(320),  dim3(256), 0, stream, ws);
    hipLaunchKernelGGL(k3_colstats, dim3(3000), dim3(256), 0, stream, ws);
    hipLaunchKernelGGL(k4_vtidal,   dim3(640),  dim3(256), 0, stream, image, ws);
    hipLaunchKernelGGL(k5_logit,    dim3(3000), dim3(256), 0, stream, text, ws);
    hipLaunchKernelGGL(k6_vns,      dim3(320),  dim3(256), 0, stream, image, ws);
    hipLaunchKernelGGL(k7_em,       dim3(320),  dim3(256), 0, stream, text, ws);
    hipLaunchKernelGGL(k8_final,    dim3(8),    dim3(256), 0, stream, ws);
    hipLaunchKernelGGL(k9_out,      dim3(1),    dim3(64),  0, stream, ws, out);
}

// Round 4
// 286.428 us; speedup vs baseline: 6.0257x; 1.0487x over previous
//
#include <hip/hip_runtime.h>
#include <hip/hip_bf16.h>
#include <math.h>

// Shapes (fixed per reference): B=40, M=8, D=256, H=16x16 -> HW=256, L=15
// Blocks: 8 blocks of 5 samples. Per block: R = 2048 regions, T = 75 tokens.
#define NG 8
#define NB5 5
#define NM 8
#define NHW 256
#define NR 2048
#define ND 256
#define NL 15
#define NT 75
#define NGB 40

// workspace layout (in floats)
#define OFF_S    0                         // s [gb][t][r], aliased later as VTP [gb][m][t][d]
#define SZ_S     (NGB*NT*NR)               // 6,144,000
#define OFF_W    (OFF_S + SZ_S)            // alpha [gb][t][r]
#define OFF_RMAX (OFF_W + SZ_S)            // [gb][seg][r]
#define SZ_RST   (NGB*5*NR)                // 409,600
#define OFF_RSUM (OFF_RMAX + SZ_RST)
#define OFF_SD   (OFF_RSUM + SZ_RST)       // [gb][m][t]
#define SZ_SD    (NGB*NM*NT)
#define OFF_VNS  (OFF_SD + SZ_SD)          // [gb][m][d]
#define SZ_VNS   (NGB*NM*ND)
#define OFF_LG   (OFF_VNS + SZ_VNS)        // logit [gb][t]
#define SZ_LG    (NGB*NT)
#define OFF_LG2  (OFF_LG + SZ_LG)          // logit2 [gb][m][s]
#define SZ_LG2   (NGB*NM*5)
#define OFF_BETA (OFF_LG2 + SZ_LG2)        // [gb][m][t]
#define SZ_BETA  (NGB*NM*NT)
#define OFF_BLK  (OFF_BETA + SZ_BETA)      // [g]

// Wave-butterfly tail: lane t combines with lane t+s — identical pairings to
// the LDS tree red[t] op= red[t+s], so results are BITWISE identical.
#define SHFL_TAIL_ADD(V)                                                       \
    V += __shfl_down(V, 32); V += __shfl_down(V, 16); V += __shfl_down(V, 8);  \
    V += __shfl_down(V, 4);  V += __shfl_down(V, 2);  V += __shfl_down(V, 1);
#define SHFL_TAIL_MAX(V)                                                       \
    V = fmaxf(V, __shfl_down(V, 32)); V = fmaxf(V, __shfl_down(V, 16));        \
    V = fmaxf(V, __shfl_down(V, 8));  V = fmaxf(V, __shfl_down(V, 4));         \
    V = fmaxf(V, __shfl_down(V, 2));  V = fmaxf(V, __shfl_down(V, 1));

// K1: s[gb][t][m*256+hw] = sum_d v[r][d]*e[t][d].
// Round-0 PROVEN version verbatim (66us). Rounds 1-3 showed: (a) any
// restructure that raises register demand spills the K-loop (min-waves>=3
// clamps the allocator); (b) the LDS-free scalar-operand variant is the same
// speed (latency-bound plateau ~66-70us either way). Leave it.
__global__ __launch_bounds__(256, 2) void k1_gemm_s(const float* __restrict__ image,
                                                    const float* __restrict__ text,
                                                    float* __restrict__ ws) {
    __shared__ __align__(16) float A[32][260];   // [dd][hw]
    __shared__ __align__(16) float Et[32][52];   // [dd][w*12 + j]  (wave-padded)
    float* Sg = ws + OFF_S;
    int blk = blockIdx.x;
    int th = blk >= 320 ? 1 : 0;
    int rest = blk - th * 320;
    int m = rest & 7, gb = rest >> 3;
    int g = gb / 5;
    int tb = th * 40;                      // block covers t in [tb, tb+40)
    const float* cell = image + (size_t)(gb * 8 + m) * ND * NHW; // [d][hw]
    int tid = threadIdx.x;
    int lane = tid & 63;
    int w = __builtin_amdgcn_readfirstlane(tid >> 6); // 0..3; wave owns t = tb+w*10+j
    int hw4 = lane * 4;
    int arow = tid >> 6;          // 0..3, A-row base (dd = arow + 4*i)
    int acol = (tid & 63) * 4;    // A col (float4)
    int edd  = tid & 31;          // Et dd
    int etc0 = tid >> 5;          // tcl = etc0 + 8*i
    float4 acc[10];
#pragma unroll
    for (int j = 0; j < 10; ++j) acc[j] = make_float4(0.f, 0.f, 0.f, 0.f);
    float4 p0, p1, p2, p3, p4, p5, p6, p7;
    float e0, e1, e2, e3, e4;
    const float* tbase = text + (size_t)g * 75 * 256;
#define K1_T(I) ((tb + etc0 + 8 * (I)) > 74 ? 74 : (tb + etc0 + 8 * (I)))
#define K1_LOAD(D0)                                                              \
    p0 = *(const float4*)&cell[(size_t)((D0) + arow +  0) * 256 + acol];         \
    p1 = *(const float4*)&cell[(size_t)((D0) + arow +  4) * 256 + acol];         \
    p2 = *(const float4*)&cell[(size_t)((D0) + arow +  8) * 256 + acol];         \
    p3 = *(const float4*)&cell[(size_t)((D0) + arow + 12) * 256 + acol];         \
    p4 = *(const float4*)&cell[(size_t)((D0) + arow + 16) * 256 + acol];         \
    p5 = *(const float4*)&cell[(size_t)((D0) + arow + 20) * 256 + acol];         \
    p6 = *(const float4*)&cell[(size_t)((D0) + arow + 24) * 256 + acol];         \
    p7 = *(const float4*)&cell[(size_t)((D0) + arow + 28) * 256 + acol];         \
    e0 = tbase[(size_t)K1_T(0) * 256 + (D0) + edd];                              \
    e1 = tbase[(size_t)K1_T(1) * 256 + (D0) + edd];                              \
    e2 = tbase[(size_t)K1_T(2) * 256 + (D0) + edd];                              \
    e3 = tbase[(size_t)K1_T(3) * 256 + (D0) + edd];                              \
    e4 = tbase[(size_t)K1_T(4) * 256 + (D0) + edd];
#define K1_ECOL(I) (((etc0 + 8 * (I)) / 10) * 12 + ((etc0 + 8 * (I)) % 10))
    K1_LOAD(0)
    for (int c = 0; c < 8; ++c) {
        __syncthreads();
        *(float4*)&A[arow +  0][acol] = p0;
        *(float4*)&A[arow +  4][acol] = p1;
        *(float4*)&A[arow +  8][acol] = p2;
        *(float4*)&A[arow + 12][acol] = p3;
        *(float4*)&A[arow + 16][acol] = p4;
        *(float4*)&A[arow + 20][acol] = p5;
        *(float4*)&A[arow + 24][acol] = p6;
        *(float4*)&A[arow + 28][acol] = p7;
        Et[edd][K1_ECOL(0)] = e0;
        Et[edd][K1_ECOL(1)] = e1;
        Et[edd][K1_ECOL(2)] = e2;
        Et[edd][K1_ECOL(3)] = e3;
        Et[edd][K1_ECOL(4)] = e4;
        __syncthreads();
        if (c < 7) { K1_LOAD((c + 1) * 32) }
        for (int dd = 0; dd < 32; ++dd) {
            float4 av = *(const float4*)&A[dd][hw4];
            float4 q0 = *(const float4*)&Et[dd][w * 12];
            float4 q1 = *(const float4*)&Et[dd][w * 12 + 4];
            float2 q2 = *(const float2*)&Et[dd][w * 12 + 8];
            float ev[10] = {q0.x, q0.y, q0.z, q0.w, q1.x, q1.y, q1.z, q1.w, q2.x, q2.y};
#pragma unroll
            for (int j = 0; j < 10; ++j) {
                acc[j].x += av.x * ev[j]; acc[j].y += av.y * ev[j];
                acc[j].z += av.z * ev[j]; acc[j].w += av.w * ev[j];
            }
        }
    }
#undef K1_LOAD
#undef K1_T
#undef K1_ECOL
#pragma unroll
    for (int j = 0; j < 10; ++j) {
        int t = tb + w * 10 + j;
        if (t < 75)
            *(float4*)&Sg[((size_t)gb * 75 + t) * 2048 + m * 256 + hw4] = acc[j];
    }
}

// K2: per-(r,seg) max/sumexp over the 15 tokens of the segment.
__global__ __launch_bounds__(256) void k2_rowstats(float* __restrict__ ws) {
    const float* Sg = ws + OFF_S;
    float* RMAX = ws + OFF_RMAX;
    float* RSUM = ws + OFF_RSUM;
    int blk = blockIdx.x;
    int m = blk & 7, gb = blk >> 3;
    int r = m * 256 + threadIdx.x;
    const float* base = Sg + (size_t)gb * 75 * 2048 + r;
    for (int seg = 0; seg < 5; ++seg) {
        float v[15]; float mx = -1e30f;
#pragma unroll
        for (int l = 0; l < 15; ++l) {
            v[l] = base[(size_t)(seg * 15 + l) * 2048];
            mx = fmaxf(mx, v[l]);
        }
        float sm = 0.f;
#pragma unroll
        for (int l = 0; l < 15; ++l) sm += __expf(v[l] - mx);
        RMAX[((size_t)gb * 5 + seg) * 2048 + r] = mx;
        RSUM[((size_t)gb * 5 + seg) * 2048 + r] = sm;
    }
}

// K3: per (gb,t) column over r=2048. Reductions rewritten: each 256-tree is
// 1 LDS level (+128) + 1 register level (+64) + 6 shfl_down steps — bitwise
// identical pairings to the old 8-barrier LDS tree. Independent trees
// (lse,lsnt) fused to share barrier levels. ~34 syncthreads -> ~10.
__global__ __launch_bounds__(256) void k3_colstats(float* __restrict__ ws) {
    __shared__ float redA[256];
    __shared__ float redB[256];
    __shared__ float red8[8][256];
    __shared__ float bc[2];
    const float* Sg = ws + OFF_S;
    const float* RMAX = ws + OFF_RMAX;
    const float* RSUM = ws + OFF_RSUM;
    float* W = ws + OFF_W;
    float* SD = ws + OFF_SD;
    int blk = blockIdx.x;           // t + 75*gb
    int t = blk % 75, gb = blk / 75;
    int seg = t / 15;
    int tid = threadIdx.x;
    const float* col = Sg + ((size_t)gb * 75 + t) * 2048;
    const float* rmx = RMAX + ((size_t)gb * 5 + seg) * 2048;
    const float* rsm = RSUM + ((size_t)gb * 5 + seg) * 2048;
    float sv[8], ent[8];
    float lmax = -1e30f, lsnt = 0.f;
#pragma unroll
    for (int k = 0; k < 8; ++k) {
        int r = tid + 256 * k;
        float s = col[r];
        sv[k] = s;
        float snt = 4.f * __expf(s - rmx[r]) / rsm[r];
        float e = __expf(snt);
        ent[k] = e;
        lsnt += e;
        lmax = fmaxf(lmax, s);
    }
    // colmax tree
    redA[tid] = lmax; __syncthreads();
    if (tid < 128) redA[tid] = fmaxf(redA[tid], redA[tid + 128]);
    __syncthreads();
    if (tid < 64) {
        float v = fmaxf(redA[tid], redA[tid + 64]);
        SHFL_TAIL_MAX(v)
        if (tid == 0) bc[0] = v;
    }
    __syncthreads();
    float cmax = bc[0];
    float pe[8]; float lse = 0.f;
#pragma unroll
    for (int k = 0; k < 8; ++k) { pe[k] = __expf(sv[k] - cmax); lse += pe[k]; }
    // csum (lse) + csnt (lsnt) trees, fused barrier levels
    redA[tid] = lse; redB[tid] = lsnt; __syncthreads();
    if (tid < 128) { redA[tid] += redA[tid + 128]; redB[tid] += redB[tid + 128]; }
    __syncthreads();
    if (tid < 64) {
        float a = redA[tid] + redA[tid + 64];
        float b = redB[tid] + redB[tid + 64];
        SHFL_TAIL_ADD(a)
        SHFL_TAIL_ADD(b)
        if (tid == 0) { bc[0] = 1.f / b; bc[1] = 1.f / a; }  // inv=1/csnt, icsum=1/csum
    }
    __syncthreads();
    float inv = bc[0], icsum = bc[1];
#pragma unroll
    for (int k = 0; k < 8; ++k)
        W[((size_t)gb * 75 + t) * 2048 + tid + 256 * k] = ent[k] * inv;
#pragma unroll
    for (int k = 0; k < 8; ++k) red8[k][tid] = __expf(pe[k] * icsum);
    __syncthreads();
    if (tid < 128) {
#pragma unroll
        for (int k = 0; k < 8; ++k) red8[k][tid] += red8[k][tid + 128];
    }
    __syncthreads();
    if (tid < 64) {
        float v[8];
#pragma unroll
        for (int k = 0; k < 8; ++k) v[k] = red8[k][tid] + red8[k][tid + 64];
#pragma unroll
        for (int k = 0; k < 8; ++k) { SHFL_TAIL_ADD(v[k]) }
        if (tid == 0) {
#pragma unroll
            for (int k = 0; k < 8; ++k)
                SD[((size_t)gb * 8 + k) * 75 + t] = v[k];
        }
    }
}

// K4: v_tidal partials per m-cell: VTP[gb][m][t][d] = sum_{r in cell} alpha[r][t]*v[r][d].
// Round-0 PROVEN version, verbatim (65us, VGPR 72, no spill).
__global__ __launch_bounds__(256, 2) void k4_vtidal(const float* __restrict__ image,
                                                    float* __restrict__ ws) {
    __shared__ __align__(16) float V[32][260];  // [rr][d]
    __shared__ __align__(16) float WtT[32][52]; // [rr][w*12 + j]
    const float* W = ws + OFF_W;
    float* VTP = ws + OFF_S; // s is dead; reuse
    int blk = blockIdx.x;
    int th = blk >= 320 ? 1 : 0;
    int rest = blk - th * 320;
    int m = rest & 7, gb = rest >> 3;
    int tb = th * 40;
    const float* cell = image + (size_t)(gb * 8 + m) * ND * NHW; // [d][hw]
    int tid = threadIdx.x;
    int lane = tid & 63;
    int w = __builtin_amdgcn_readfirstlane(tid >> 6); // 0..3; wave owns t = tb+w*10+j
    int d4 = lane * 4;
    int rr4  = (tid & 7) * 4;     // V rr base for this thread's float4
    int drow = tid >> 3;          // d = drow + 32*i
    int wrr  = tid & 31;          // WtT rr
    int wtc0 = tid >> 5;          // tcl = wtc0 + 8*i
    float4 acc[10];
#pragma unroll
    for (int j = 0; j < 10; ++j) acc[j] = make_float4(0.f, 0.f, 0.f, 0.f);
    const float* wb = W + (size_t)gb * 75 * 2048 + m * 256;
    float4 p0, p1, p2, p3, p4, p5, p6, p7;
    float w0, w1, w2, w3, w4;
#define K4_T(I) ((tb + wtc0 + 8 * (I)) > 74 ? 74 : (tb + wtc0 + 8 * (I)))
#define K4_LOAD(RC)                                                               \
    p0 = *(const float4*)&cell[(size_t)(drow +   0) * 256 + (RC) * 32 + rr4];     \
    p1 = *(const float4*)&cell[(size_t)(drow +  32) * 256 + (RC) * 32 + rr4];     \
    p2 = *(const float4*)&cell[(size_t)(drow +  64) * 256 + (RC) * 32 + rr4];     \
    p3 = *(const float4*)&cell[(size_t)(drow +  96) * 256 + (RC) * 32 + rr4];     \
    p4 = *(const float4*)&cell[(size_t)(drow + 128) * 256 + (RC) * 32 + rr4];     \
    p5 = *(const float4*)&cell[(size_t)(drow + 160) * 256 + (RC) * 32 + rr4];     \
    p6 = *(const float4*)&cell[(size_t)(drow + 192) * 256 + (RC) * 32 + rr4];     \
    p7 = *(const float4*)&cell[(size_t)(drow + 224) * 256 + (RC) * 32 + rr4];     \
    w0 = wb[(size_t)K4_T(0) * 2048 + (RC) * 32 + wrr];                            \
    w1 = wb[(size_t)K4_T(1) * 2048 + (RC) * 32 + wrr];                            \
    w2 = wb[(size_t)K4_T(2) * 2048 + (RC) * 32 + wrr];                            \
    w3 = wb[(size_t)K4_T(3) * 2048 + (RC) * 32 + wrr];                            \
    w4 = wb[(size_t)K4_T(4) * 2048 + (RC) * 32 + wrr];
#define K4_WCOL(I) (((wtc0 + 8 * (I)) / 10) * 12 + ((wtc0 + 8 * (I)) % 10))
#define K4_VST(P, DOFF)                                                           \
    V[rr4 + 0][drow + (DOFF)] = (P).x;                                            \
    V[rr4 + 1][drow + (DOFF)] = (P).y;                                            \
    V[rr4 + 2][drow + (DOFF)] = (P).z;                                            \
    V[rr4 + 3][drow + (DOFF)] = (P).w;
    K4_LOAD(0)
    for (int rc = 0; rc < 8; ++rc) {
        __syncthreads();
        K4_VST(p0,   0) K4_VST(p1,  32) K4_VST(p2,  64) K4_VST(p3,  96)
        K4_VST(p4, 128) K4_VST(p5, 160) K4_VST(p6, 192) K4_VST(p7, 224)
        WtT[wrr][K4_WCOL(0)] = w0;
        WtT[wrr][K4_WCOL(1)] = w1;
        WtT[wrr][K4_WCOL(2)] = w2;
        WtT[wrr][K4_WCOL(3)] = w3;
        WtT[wrr][K4_WCOL(4)] = w4;
        __syncthreads();
        if (rc < 7) { K4_LOAD(rc + 1) }
        for (int rr = 0; rr < 32; ++rr) {
            float4 vv = *(const float4*)&V[rr][d4];
            float4 q0 = *(const float4*)&WtT[rr][w * 12];
            float4 q1 = *(const float4*)&WtT[rr][w * 12 + 4];
            float2 q2 = *(const float2*)&WtT[rr][w * 12 + 8];
            float wv[10] = {q0.x, q0.y, q0.z, q0.w, q1.x, q1.y, q1.z, q1.w, q2.x, q2.y};
#pragma unroll
            for (int j = 0; j < 10; ++j) {
                acc[j].x += vv.x * wv[j]; acc[j].y += vv.y * wv[j];
                acc[j].z += vv.z * wv[j]; acc[j].w += vv.w * wv[j];
            }
        }
    }
#undef K4_LOAD
#undef K4_T
#undef K4_WCOL
#undef K4_VST
#pragma unroll
    for (int j = 0; j < 10; ++j) {
        int t = tb + w * 10 + j;
        if (t < 75)
            *(float4*)&VTP[((size_t)(gb * 8 + m) * 75 + t) * 256 + d4] = acc[j];
    }
}

// K5: v_tidal = sum_m VTP; logit[gb][t] = <vt/||vt||, e/||e||>.
// Three independent trees fused into shared barrier levels + shfl tails:
// ~30 syncthreads -> 3. Bitwise-identical pairings per value.
__global__ __launch_bounds__(256) void k5_logit(const float* __restrict__ text,
                                                float* __restrict__ ws) {
    __shared__ float rA[256], rB[256], rC[256];
    const float* VTP = ws + OFF_S;
    float* LG = ws + OFF_LG;
    int blk = blockIdx.x;
    int t = blk % 75, gb = blk / 75, g = gb / 5;
    int tid = threadIdx.x;
    float vt = 0.f;
#pragma unroll
    for (int m = 0; m < 8; ++m)
        vt += VTP[((size_t)(gb * 8 + m) * 75 + t) * 256 + tid];
    int seg = t / 15, l = t % 15;
    float ev = text[((size_t)(g * 5 + seg) * 15 + l) * 256 + tid];
    rA[tid] = vt * vt; rB[tid] = ev * ev; rC[tid] = vt * ev;
    __syncthreads();
    if (tid < 128) {
        rA[tid] += rA[tid + 128];
        rB[tid] += rB[tid + 128];
        rC[tid] += rC[tid + 128];
    }
    __syncthreads();
    if (tid < 64) {
        float a = rA[tid] + rA[tid + 64];
        float b = rB[tid] + rB[tid + 64];
        float c = rC[tid] + rC[tid + 64];
        SHFL_TAIL_ADD(a)
        SHFL_TAIL_ADD(b)
        SHFL_TAIL_ADD(c)
        if (tid == 0)
            LG[gb * 75 + t] = c / (fmaxf(sqrtf(a), 1e-12f) * fmaxf(sqrtf(b), 1e-12f));
    }
}

// K6: vns[gb][m][d] = sum_hw v[hw][d]/max(||v[hw]||,1e-12)
__global__ __launch_bounds__(256) void k6_vns(const float* __restrict__ image,
                                              float* __restrict__ ws) {
    __shared__ float A[32][257];
    __shared__ float rn[256];
    __shared__ float ps[256];
    float* VNS = ws + OFF_VNS;
    int blk = blockIdx.x;
    int m = blk & 7, gb = blk >> 3;
    const float* cell = image + (size_t)(gb * 8 + m) * ND * NHW;
    int tid = threadIdx.x;
    float nsq = 0.f;
    for (int d = 0; d < 256; ++d) {
        float v = cell[d * 256 + tid];
        nsq += v * v;
    }
    rn[tid] = 1.f / fmaxf(sqrtf(nsq), 1e-12f);
    int d_loc = tid & 31, sub = tid >> 5; // 8 subs x 32 d
    for (int d0 = 0; d0 < 256; d0 += 32) {
        __syncthreads();
#pragma unroll
        for (int i = 0; i < 32; ++i) A[i][tid] = cell[(d0 + i) * 256 + tid];
        __syncthreads();
        float partial = 0.f;
#pragma unroll
        for (int k = 0; k < 32; ++k) {
            int hw = sub + 8 * k;
            partial += A[d_loc][hw] * rn[hw];
        }
        ps[tid] = partial; __syncthreads();
        if (tid < 128) ps[tid] += ps[tid + 128];
        __syncthreads();
        if (tid < 64) ps[tid] += ps[tid + 64];
        __syncthreads();
        if (tid < 32)
            VNS[((size_t)gb * 8 + m) * 256 + d0 + tid] = ps[tid] + ps[tid + 32];
    }
}

// K7: beta from SD; em[s][d] = sum_l beta*e; logit2[gb][m][s] = <em/||em||, vns>/256.
// Two trees per segment fused + shfl tails: ~100 syncthreads -> ~18.
__global__ __launch_bounds__(256) void k7_em(const float* __restrict__ text,
                                             float* __restrict__ ws) {
    __shared__ float rA[256], rB[256];
    __shared__ float sdv[75];
    __shared__ float segs[5];
    __shared__ float betas[5][15];
    const float* SD = ws + OFF_SD;
    const float* VNS = ws + OFF_VNS;
    float* BETA = ws + OFF_BETA;
    float* LG2 = ws + OFF_LG2;
    int blk = blockIdx.x;
    int m = blk & 7, gb = blk >> 3, g = gb / 5;
    int tid = threadIdx.x;
    if (tid < 75) sdv[tid] = SD[((size_t)gb * 8 + m) * 75 + tid];
    __syncthreads();
    if (tid < 5) {
        float s = 0.f;
        for (int l = 0; l < 15; ++l) s += sdv[tid * 15 + l];
        segs[tid] = s;
    }
    __syncthreads();
    if (tid < 75) {
        float b = sdv[tid] / segs[tid / 15];
        betas[tid / 15][tid % 15] = b;
        BETA[((size_t)gb * 8 + m) * 75 + tid] = b;
    }
    __syncthreads();
    float vns = VNS[((size_t)gb * 8 + m) * 256 + tid];
    for (int s = 0; s < 5; ++s) {
        float em = 0.f;
#pragma unroll
        for (int l = 0; l < 15; ++l)
            em += betas[s][l] * text[((size_t)(g * 5 + s) * 15 + l) * 256 + tid];
        rA[tid] = em * em; rB[tid] = em * vns;
        __syncthreads();
        if (tid < 128) { rA[tid] += rA[tid + 128]; rB[tid] += rB[tid + 128]; }
        __syncthreads();
        if (tid < 64) {
            float a = rA[tid] + rA[tid + 64];
            float b = rB[tid] + rB[tid + 64];
            SHFL_TAIL_ADD(a)
            SHFL_TAIL_ADD(b)
            if (tid == 0)
                LG2[((size_t)gb * 8 + m) * 5 + s] =
                    b / fmaxf(sqrtf(a), 1e-12f) * (1.f / 256.f);
        }
        __syncthreads();  // rA/rB reused next segment
    }
}

// K8: per-g block assembly -> BLK[g]
__global__ __launch_bounds__(256) void k8_final(float* __restrict__ ws) {
    __shared__ float lsm[5][5];
    __shared__ float offsq[5][64];
    __shared__ float regs[5];
    const float* LG = ws + OFF_LG;
    const float* LG2 = ws + OFF_LG2;
    const float* BETA = ws + OFF_BETA;
    float* BLK = ws + OFF_BLK;
    int g = blockIdx.x;
    int tid = threadIdx.x;
    if (tid < 25) {
        int b = tid / 5, s = tid % 5;
        int gb = g * 5 + b;
        float s1 = 0.f;
        for (int l = 0; l < 15; ++l) s1 += expf(LG[gb * 75 + s * 15 + l]);
        float s2 = 0.f;
        for (int mm = 0; mm < 8; ++mm) s2 += expf(LG2[((size_t)gb * 8 + mm) * 5 + s]);
        float l1 = logf(powf(s1, 0.2f) + 1e-10f);
        float l2 = logf(powf(s2, 0.2f) + 1e-10f);
        lsm[b][s] = 10.f * (l1 + l2);
    }
    for (int p = tid; p < 320; p += 256) {
        int b = p >> 6, mn = p & 63, mm = mn >> 3, nn = mn & 7;
        int gb = g * 5 + b;
        const float* bm = BETA + ((size_t)gb * 8 + mm) * 75;
        const float* bn = BETA + ((size_t)gb * 8 + nn) * 75;
        float acc = 0.f;
        for (int t2 = 0; t2 < 75; ++t2) acc += bm[t2] * bn[t2];
        offsq[b][mn] = (mm == nn) ? 0.f : acc * acc;
    }
    __syncthreads();
    if (tid < 5) {
        float s = 0.f;
        for (int i = 0; i < 64; ++i) s += offsq[tid][i];
        regs[tid] = sqrtf(s);
    }
    __syncthreads();
    if (tid == 0) {
        float loss_reg = 0.f;
        for (int b = 0; b < 5; ++b) loss_reg += regs[b];
        loss_reg *= 0.2f;
        float pdq = 0.f, pqd = 0.f;
        for (int i = 0; i < 5; ++i) {
            float rsum = 0.f, csum = 0.f;
            for (int j = 0; j < 5; ++j) { rsum += lsm[i][j]; csum += lsm[j][i]; }
            float di = lsm[i][i];
            pdq += -logf(di / rsum + 1e-10f);
            pqd += -logf(di / csum + 1e-10f);
        }
        BLK[g] = (pdq + pqd) * 0.2f + loss_reg;
    }
}

__global__ void k9_out(const float* __restrict__ ws, float* __restrict__ out) {
    if (threadIdx.x == 0) {
        float s = 0.f;
        for (int g2 = 0; g2 < 8; ++g2) s += ws[OFF_BLK + g2];
        out[0] = s / 9.f;
    }
}

extern "C" void kernel_launch(void* const* d_in, const int* in_sizes, int n_in,
                              void* d_out, int out_size, void* d_ws, size_t ws_size,
                              hipStream_t stream) {
    const float* image = (const float*)d_in[0];
    const float* text  = (const float*)d_in[1];
    float* ws = (float*)d_ws;
    float* out = (float*)d_out;
    hipLaunchKernelGGL(k1_gemm_s,   dim3(640),  dim3(256), 0, stream, image, text, ws);
    hipLaunchKernelGGL(k2_rowstats, dim3(320),  dim3(256), 0, stream, ws);
    hipLaunchKernelGGL(k3_colstats, dim3(3000), dim3(256), 0, stream, ws);
    hipLaunchKernelGGL(k4_vtidal,   dim3(640),  dim3(256), 0, stream, image, ws);
    hipLaunchKernelGGL(k5_logit,    dim3(3000), dim3(256), 0, stream, text, ws);
    hipLaunchKernelGGL(k6_vns,      dim3(320),  dim3(256), 0, stream, image, ws);
    hipLaunchKernelGGL(k7_em,       dim3(320),  dim3(256), 0, stream, text, ws);
    hipLaunchKernelGGL(k8_final,    dim3(8),    dim3(256), 0, stream, ws);
    hipLaunchKernelGGL(k9_out,      dim3(1),    dim3(64),  0, stream, ws, out);
}

// Round 5
// 272.475 us; speedup vs baseline: 6.3342x; 1.0512x over previous
//
#include <hip/hip_runtime.h>
#include <hip/hip_bf16.h>
#include <math.h>

// Shapes (fixed per reference): B=40, M=8, D=256, H=16x16 -> HW=256, L=15
// Blocks: 8 blocks of 5 samples. Per block: R = 2048 regions, T = 75 tokens.
#define NG 8
#define NB5 5
#define NM 8
#define NHW 256
#define NR 2048
#define ND 256
#define NL 15
#define NT 75
#define NGB 40

// workspace layout (in floats)
#define OFF_S    0                         // s [gb][t][r], aliased later as VTP [gb][m][t][d]
#define SZ_S     (NGB*NT*NR)               // 6,144,000
#define OFF_W    (OFF_S + SZ_S)            // alpha [gb][t][r]
#define OFF_RMAX (OFF_W + SZ_S)            // [gb][seg][r]
#define SZ_RST   (NGB*5*NR)                // 409,600
#define OFF_RSUM (OFF_RMAX + SZ_RST)
#define OFF_SD   (OFF_RSUM + SZ_RST)       // [gb][m][t]
#define SZ_SD    (NGB*NM*NT)
#define OFF_VNS  (OFF_SD + SZ_SD)          // [gb][m][d]; ALSO stages NSQ (k1->k6)
#define SZ_VNS   (NGB*NM*ND)
#define OFF_LG   (OFF_VNS + SZ_VNS)        // logit [gb][t]
#define SZ_LG    (NGB*NT)
#define OFF_LG2  (OFF_LG + SZ_LG)          // logit2 [gb][m][s]
#define SZ_LG2   (NGB*NM*5)
#define OFF_BETA (OFF_LG2 + SZ_LG2)        // [gb][m][t]
#define SZ_BETA  (NGB*NM*NT)
#define OFF_BLK  (OFF_BETA + SZ_BETA)      // [g]

// Wave-butterfly tail: lane t combines with lane t+s — identical pairings to
// the LDS tree red[t] op= red[t+s], so results are BITWISE identical.
#define SHFL_TAIL_ADD(V)                                                       \
    V += __shfl_down(V, 32); V += __shfl_down(V, 16); V += __shfl_down(V, 8);  \
    V += __shfl_down(V, 4);  V += __shfl_down(V, 2);  V += __shfl_down(V, 1);
#define SHFL_TAIL_MAX(V)                                                       \
    V = fmaxf(V, __shfl_down(V, 32)); V = fmaxf(V, __shfl_down(V, 16));        \
    V = fmaxf(V, __shfl_down(V, 8));  V = fmaxf(V, __shfl_down(V, 4));         \
    V = fmaxf(V, __shfl_down(V, 2));  V = fmaxf(V, __shfl_down(V, 1));

// K1: s[gb][t][m*256+hw] = sum_d v[r][d]*e[t][d].
// Round-0 proven structure. NEW: accumulates nsq[hw] = sum_d v[d][hw]^2 from
// the SAME av reads in the SAME ascending-d order as k6's original first pass
// (bitwise identical), and the th==0/w==0 wave writes it into the VNS slot
// (dead until k6, which consumes it before overwriting). Kills k6's 80MB
// re-read of the image. +4 FMA/dd is absorbed by the latency-bound loop.
__global__ __launch_bounds__(256, 2) void k1_gemm_s(const float* __restrict__ image,
                                                    const float* __restrict__ text,
                                                    float* __restrict__ ws) {
    __shared__ __align__(16) float A[32][260];   // [dd][hw]
    __shared__ __align__(16) float Et[32][52];   // [dd][w*12 + j]  (wave-padded)
    float* Sg = ws + OFF_S;
    int blk = blockIdx.x;
    int th = blk >= 320 ? 1 : 0;
    int rest = blk - th * 320;
    int m = rest & 7, gb = rest >> 3;
    int g = gb / 5;
    int tb = th * 40;                      // block covers t in [tb, tb+40)
    const float* cell = image + (size_t)(gb * 8 + m) * ND * NHW; // [d][hw]
    int tid = threadIdx.x;
    int lane = tid & 63;
    int w = __builtin_amdgcn_readfirstlane(tid >> 6); // 0..3; wave owns t = tb+w*10+j
    int hw4 = lane * 4;
    int arow = tid >> 6;          // 0..3, A-row base (dd = arow + 4*i)
    int acol = (tid & 63) * 4;    // A col (float4)
    int edd  = tid & 31;          // Et dd
    int etc0 = tid >> 5;          // tcl = etc0 + 8*i
    float4 acc[10];
#pragma unroll
    for (int j = 0; j < 10; ++j) acc[j] = make_float4(0.f, 0.f, 0.f, 0.f);
    float4 nsqa = make_float4(0.f, 0.f, 0.f, 0.f);
    float4 p0, p1, p2, p3, p4, p5, p6, p7;
    float e0, e1, e2, e3, e4;
    const float* tbase = text + (size_t)g * 75 * 256;
#define K1_T(I) ((tb + etc0 + 8 * (I)) > 74 ? 74 : (tb + etc0 + 8 * (I)))
#define K1_LOAD(D0)                                                              \
    p0 = *(const float4*)&cell[(size_t)((D0) + arow +  0) * 256 + acol];         \
    p1 = *(const float4*)&cell[(size_t)((D0) + arow +  4) * 256 + acol];         \
    p2 = *(const float4*)&cell[(size_t)((D0) + arow +  8) * 256 + acol];         \
    p3 = *(const float4*)&cell[(size_t)((D0) + arow + 12) * 256 + acol];         \
    p4 = *(const float4*)&cell[(size_t)((D0) + arow + 16) * 256 + acol];         \
    p5 = *(const float4*)&cell[(size_t)((D0) + arow + 20) * 256 + acol];         \
    p6 = *(const float4*)&cell[(size_t)((D0) + arow + 24) * 256 + acol];         \
    p7 = *(const float4*)&cell[(size_t)((D0) + arow + 28) * 256 + acol];         \
    e0 = tbase[(size_t)K1_T(0) * 256 + (D0) + edd];                              \
    e1 = tbase[(size_t)K1_T(1) * 256 + (D0) + edd];                              \
    e2 = tbase[(size_t)K1_T(2) * 256 + (D0) + edd];                              \
    e3 = tbase[(size_t)K1_T(3) * 256 + (D0) + edd];                              \
    e4 = tbase[(size_t)K1_T(4) * 256 + (D0) + edd];
#define K1_ECOL(I) (((etc0 + 8 * (I)) / 10) * 12 + ((etc0 + 8 * (I)) % 10))
    K1_LOAD(0)
    for (int c = 0; c < 8; ++c) {
        __syncthreads();
        *(float4*)&A[arow +  0][acol] = p0;
        *(float4*)&A[arow +  4][acol] = p1;
        *(float4*)&A[arow +  8][acol] = p2;
        *(float4*)&A[arow + 12][acol] = p3;
        *(float4*)&A[arow + 16][acol] = p4;
        *(float4*)&A[arow + 20][acol] = p5;
        *(float4*)&A[arow + 24][acol] = p6;
        *(float4*)&A[arow + 28][acol] = p7;
        Et[edd][K1_ECOL(0)] = e0;
        Et[edd][K1_ECOL(1)] = e1;
        Et[edd][K1_ECOL(2)] = e2;
        Et[edd][K1_ECOL(3)] = e3;
        Et[edd][K1_ECOL(4)] = e4;
        __syncthreads();
        if (c < 7) { K1_LOAD((c + 1) * 32) }
        for (int dd = 0; dd < 32; ++dd) {
            float4 av = *(const float4*)&A[dd][hw4];
            nsqa.x += av.x * av.x; nsqa.y += av.y * av.y;
            nsqa.z += av.z * av.z; nsqa.w += av.w * av.w;
            float4 q0 = *(const float4*)&Et[dd][w * 12];
            float4 q1 = *(const float4*)&Et[dd][w * 12 + 4];
            float2 q2 = *(const float2*)&Et[dd][w * 12 + 8];
            float ev[10] = {q0.x, q0.y, q0.z, q0.w, q1.x, q1.y, q1.z, q1.w, q2.x, q2.y};
#pragma unroll
            for (int j = 0; j < 10; ++j) {
                acc[j].x += av.x * ev[j]; acc[j].y += av.y * ev[j];
                acc[j].z += av.z * ev[j]; acc[j].w += av.w * ev[j];
            }
        }
    }
#undef K1_LOAD
#undef K1_T
#undef K1_ECOL
#pragma unroll
    for (int j = 0; j < 10; ++j) {
        int t = tb + w * 10 + j;
        if (t < 75)
            *(float4*)&Sg[((size_t)gb * 75 + t) * 2048 + m * 256 + hw4] = acc[j];
    }
    if (th == 0 && w == 0)
        *(float4*)&ws[OFF_VNS + (size_t)(gb * 8 + m) * 256 + hw4] = nsqa;
}

// K2: per-(r,seg) max/sumexp. Regrid 320 -> 1600 blocks (gb x seg x chunk,
// 1 r per thread): 1.25 -> 6.25 blocks/CU. Identical per-(r,seg) math.
__global__ __launch_bounds__(256) void k2_rowstats(float* __restrict__ ws) {
    const float* Sg = ws + OFF_S;
    float* RMAX = ws + OFF_RMAX;
    float* RSUM = ws + OFF_RSUM;
    int blk = blockIdx.x;               // chunk + 8*(seg + 5*gb)
    int chunk = blk & 7;
    int rest = blk >> 3;
    int seg = rest % 5, gb = rest / 5;
    int r = chunk * 256 + threadIdx.x;
    const float* base = Sg + (size_t)gb * 75 * 2048 + r;
    float v[15]; float mx = -1e30f;
#pragma unroll
    for (int l = 0; l < 15; ++l) {
        v[l] = base[(size_t)(seg * 15 + l) * 2048];
        mx = fmaxf(mx, v[l]);
    }
    float sm = 0.f;
#pragma unroll
    for (int l = 0; l < 15; ++l) sm += __expf(v[l] - mx);
    RMAX[((size_t)gb * 5 + seg) * 2048 + r] = mx;
    RSUM[((size_t)gb * 5 + seg) * 2048 + r] = sm;
}

// K3: per (gb,t) column over r=2048. Fast fused reductions (round-4 proven).
__global__ __launch_bounds__(256) void k3_colstats(float* __restrict__ ws) {
    __shared__ float redA[256];
    __shared__ float redB[256];
    __shared__ float red8[8][256];
    __shared__ float bc[2];
    const float* Sg = ws + OFF_S;
    const float* RMAX = ws + OFF_RMAX;
    const float* RSUM = ws + OFF_RSUM;
    float* W = ws + OFF_W;
    float* SD = ws + OFF_SD;
    int blk = blockIdx.x;           // t + 75*gb
    int t = blk % 75, gb = blk / 75;
    int seg = t / 15;
    int tid = threadIdx.x;
    const float* col = Sg + ((size_t)gb * 75 + t) * 2048;
    const float* rmx = RMAX + ((size_t)gb * 5 + seg) * 2048;
    const float* rsm = RSUM + ((size_t)gb * 5 + seg) * 2048;
    float sv[8], ent[8];
    float lmax = -1e30f, lsnt = 0.f;
#pragma unroll
    for (int k = 0; k < 8; ++k) {
        int r = tid + 256 * k;
        float s = col[r];
        sv[k] = s;
        float snt = 4.f * __expf(s - rmx[r]) / rsm[r];
        float e = __expf(snt);
        ent[k] = e;
        lsnt += e;
        lmax = fmaxf(lmax, s);
    }
    // colmax tree
    redA[tid] = lmax; __syncthreads();
    if (tid < 128) redA[tid] = fmaxf(redA[tid], redA[tid + 128]);
    __syncthreads();
    if (tid < 64) {
        float v = fmaxf(redA[tid], redA[tid + 64]);
        SHFL_TAIL_MAX(v)
        if (tid == 0) bc[0] = v;
    }
    __syncthreads();
    float cmax = bc[0];
    float pe[8]; float lse = 0.f;
#pragma unroll
    for (int k = 0; k < 8; ++k) { pe[k] = __expf(sv[k] - cmax); lse += pe[k]; }
    // csum (lse) + csnt (lsnt) trees, fused barrier levels
    redA[tid] = lse; redB[tid] = lsnt; __syncthreads();
    if (tid < 128) { redA[tid] += redA[tid + 128]; redB[tid] += redB[tid + 128]; }
    __syncthreads();
    if (tid < 64) {
        float a = redA[tid] + redA[tid + 64];
        float b = redB[tid] + redB[tid + 64];
        SHFL_TAIL_ADD(a)
        SHFL_TAIL_ADD(b)
        if (tid == 0) { bc[0] = 1.f / b; bc[1] = 1.f / a; }  // inv=1/csnt, icsum=1/csum
    }
    __syncthreads();
    float inv = bc[0], icsum = bc[1];
#pragma unroll
    for (int k = 0; k < 8; ++k)
        W[((size_t)gb * 75 + t) * 2048 + tid + 256 * k] = ent[k] * inv;
#pragma unroll
    for (int k = 0; k < 8; ++k) red8[k][tid] = __expf(pe[k] * icsum);
    __syncthreads();
    if (tid < 128) {
#pragma unroll
        for (int k = 0; k < 8; ++k) red8[k][tid] += red8[k][tid + 128];
    }
    __syncthreads();
    if (tid < 64) {
        float v[8];
#pragma unroll
        for (int k = 0; k < 8; ++k) v[k] = red8[k][tid] + red8[k][tid + 64];
#pragma unroll
        for (int k = 0; k < 8; ++k) { SHFL_TAIL_ADD(v[k]) }
        if (tid == 0) {
#pragma unroll
            for (int k = 0; k < 8; ++k)
                SD[((size_t)gb * 8 + k) * 75 + t] = v[k];
        }
    }
}

// K4: v_tidal partials per m-cell. Round-0 structure; NEW: V tile stored with
// an XOR swizzle at float4-block granularity (block c' = c ^ ((rr>>2)&7),
// row stride 256). Old layout: every scatter store was a 4-way bank conflict
// (rr4*stride mod 32 in {0,16} for any 16B-aligned stride) = 4.5M conflict
// cycles. Swizzled store banks = 5 independent lane-id bits -> exact 2-way
// (free); reads (uniform rr) stay contiguous-permuted 1KB, conflict-free,
// 16B-aligned. Pure layout change: bitwise-identical results.
__global__ __launch_bounds__(256, 2) void k4_vtidal(const float* __restrict__ image,
                                                    float* __restrict__ ws) {
    __shared__ __align__(16) float V[32 * 256];  // [rr][swizzled d-block]
    __shared__ __align__(16) float WtT[32][52];  // [rr][w*12 + j]
    const float* W = ws + OFF_W;
    float* VTP = ws + OFF_S; // s is dead; reuse
    int blk = blockIdx.x;
    int th = blk >= 320 ? 1 : 0;
    int rest = blk - th * 320;
    int m = rest & 7, gb = rest >> 3;
    int tb = th * 40;
    const float* cell = image + (size_t)(gb * 8 + m) * ND * NHW; // [d][hw]
    int tid = threadIdx.x;
    int lane = tid & 63;
    int w = __builtin_amdgcn_readfirstlane(tid >> 6); // 0..3; wave owns t = tb+w*10+j
    int d4 = lane * 4;
    int rr4  = (tid & 7) * 4;     // V rr base for this thread's float4
    int drow = tid >> 3;          // d = drow + 32*i
    int wrr  = tid & 31;          // WtT rr
    int wtc0 = tid >> 5;          // tcl = wtc0 + 8*i
    float4 acc[10];
#pragma unroll
    for (int j = 0; j < 10; ++j) acc[j] = make_float4(0.f, 0.f, 0.f, 0.f);
    const float* wb = W + (size_t)gb * 75 * 2048 + m * 256;
    float4 p0, p1, p2, p3, p4, p5, p6, p7;
    float w0, w1, w2, w3, w4;
#define K4_T(I) ((tb + wtc0 + 8 * (I)) > 74 ? 74 : (tb + wtc0 + 8 * (I)))
#define K4_LOAD(RC)                                                               \
    p0 = *(const float4*)&cell[(size_t)(drow +   0) * 256 + (RC) * 32 + rr4];     \
    p1 = *(const float4*)&cell[(size_t)(drow +  32) * 256 + (RC) * 32 + rr4];     \
    p2 = *(const float4*)&cell[(size_t)(drow +  64) * 256 + (RC) * 32 + rr4];     \
    p3 = *(const float4*)&cell[(size_t)(drow +  96) * 256 + (RC) * 32 + rr4];     \
    p4 = *(const float4*)&cell[(size_t)(drow + 128) * 256 + (RC) * 32 + rr4];     \
    p5 = *(const float4*)&cell[(size_t)(drow + 160) * 256 + (RC) * 32 + rr4];     \
    p6 = *(const float4*)&cell[(size_t)(drow + 192) * 256 + (RC) * 32 + rr4];     \
    p7 = *(const float4*)&cell[(size_t)(drow + 224) * 256 + (RC) * 32 + rr4];     \
    w0 = wb[(size_t)K4_T(0) * 2048 + (RC) * 32 + wrr];                            \
    w1 = wb[(size_t)K4_T(1) * 2048 + (RC) * 32 + wrr];                            \
    w2 = wb[(size_t)K4_T(2) * 2048 + (RC) * 32 + wrr];                            \
    w3 = wb[(size_t)K4_T(3) * 2048 + (RC) * 32 + wrr];                            \
    w4 = wb[(size_t)K4_T(4) * 2048 + (RC) * 32 + wrr];
#define K4_WCOL(I) (((wtc0 + 8 * (I)) / 10) * 12 + ((wtc0 + 8 * (I)) % 10))
// swizzled V address for (row RR, column D): block (D>>2) ^ ((RR>>2)&7)
#define K4_VADDR(RR, D) (((RR) << 8) + ((((D) >> 2) ^ (((RR) >> 2) & 7)) << 2) + ((D) & 3))
#define K4_VST(P, DOFF)                                                           \
    V[K4_VADDR(rr4 + 0, drow + (DOFF))] = (P).x;                                  \
    V[K4_VADDR(rr4 + 1, drow + (DOFF))] = (P).y;                                  \
    V[K4_VADDR(rr4 + 2, drow + (DOFF))] = (P).z;                                  \
    V[K4_VADDR(rr4 + 3, drow + (DOFF))] = (P).w;
    K4_LOAD(0)
    for (int rc = 0; rc < 8; ++rc) {
        __syncthreads();
        K4_VST(p0,   0) K4_VST(p1,  32) K4_VST(p2,  64) K4_VST(p3,  96)
        K4_VST(p4, 128) K4_VST(p5, 160) K4_VST(p6, 192) K4_VST(p7, 224)
        WtT[wrr][K4_WCOL(0)] = w0;
        WtT[wrr][K4_WCOL(1)] = w1;
        WtT[wrr][K4_WCOL(2)] = w2;
        WtT[wrr][K4_WCOL(3)] = w3;
        WtT[wrr][K4_WCOL(4)] = w4;
        __syncthreads();
        if (rc < 7) { K4_LOAD(rc + 1) }
        for (int rr = 0; rr < 32; ++rr) {
            int sr = (rr >> 2) & 7;
            float4 vv = *(const float4*)&V[(rr << 8) + ((lane ^ sr) << 2)];
            float4 q0 = *(const float4*)&WtT[rr][w * 12];
            float4 q1 = *(const float4*)&WtT[rr][w * 12 + 4];
            float2 q2 = *(const float2*)&WtT[rr][w * 12 + 8];
            float wv[10] = {q0.x, q0.y, q0.z, q0.w, q1.x, q1.y, q1.z, q1.w, q2.x, q2.y};
#pragma unroll
            for (int j = 0; j < 10; ++j) {
                acc[j].x += vv.x * wv[j]; acc[j].y += vv.y * wv[j];
                acc[j].z += vv.z * wv[j]; acc[j].w += vv.w * wv[j];
            }
        }
    }
#undef K4_LOAD
#undef K4_T
#undef K4_WCOL
#undef K4_VADDR
#undef K4_VST
#pragma unroll
    for (int j = 0; j < 10; ++j) {
        int t = tb + w * 10 + j;
        if (t < 75)
            *(float4*)&VTP[((size_t)(gb * 8 + m) * 75 + t) * 256 + d4] = acc[j];
    }
}

// K5: v_tidal = sum_m VTP; logit[gb][t] = <vt/||vt||, e/||e||>. (round-4 proven)
__global__ __launch_bounds__(256) void k5_logit(const float* __restrict__ text,
                                                float* __restrict__ ws) {
    __shared__ float rA[256], rB[256], rC[256];
    const float* VTP = ws + OFF_S;
    float* LG = ws + OFF_LG;
    int blk = blockIdx.x;
    int t = blk % 75, gb = blk / 75, g = gb / 5;
    int tid = threadIdx.x;
    float vt = 0.f;
#pragma unroll
    for (int m = 0; m < 8; ++m)
        vt += VTP[((size_t)(gb * 8 + m) * 75 + t) * 256 + tid];
    int seg = t / 15, l = t % 15;
    float ev = text[((size_t)(g * 5 + seg) * 15 + l) * 256 + tid];
    rA[tid] = vt * vt; rB[tid] = ev * ev; rC[tid] = vt * ev;
    __syncthreads();
    if (tid < 128) {
        rA[tid] += rA[tid + 128];
        rB[tid] += rB[tid + 128];
        rC[tid] += rC[tid + 128];
    }
    __syncthreads();
    if (tid < 64) {
        float a = rA[tid] + rA[tid + 64];
        float b = rB[tid] + rB[tid + 64];
        float c = rC[tid] + rC[tid + 64];
        SHFL_TAIL_ADD(a)
        SHFL_TAIL_ADD(b)
        SHFL_TAIL_ADD(c)
        if (tid == 0)
            LG[gb * 75 + t] = c / (fmaxf(sqrtf(a), 1e-12f) * fmaxf(sqrtf(b), 1e-12f));
    }
}

// K6: vns[gb][m][d] = sum_hw v[hw][d]/max(||v[hw]||,1e-12).
// SINGLE-PASS: nsq comes from k1 (staged in this very VNS slot, consumed into
// rn[] before the first barrier, then overwritten). Saves 80MB of image
// re-reads. rn values bitwise-identical to the old two-pass version.
__global__ __launch_bounds__(256) void k6_vns(const float* __restrict__ image,
                                              float* __restrict__ ws) {
    __shared__ float A[32][257];
    __shared__ float rn[256];
    __shared__ float ps[256];
    float* VNS = ws + OFF_VNS;
    int blk = blockIdx.x;
    int m = blk & 7, gb = blk >> 3;
    const float* cell = image + (size_t)(gb * 8 + m) * ND * NHW;
    int tid = threadIdx.x;
    float nsq = VNS[((size_t)gb * 8 + m) * 256 + tid];   // staged by k1
    rn[tid] = 1.f / fmaxf(sqrtf(nsq), 1e-12f);
    int d_loc = tid & 31, sub = tid >> 5; // 8 subs x 32 d
    for (int d0 = 0; d0 < 256; d0 += 32) {
        __syncthreads();
#pragma unroll
        for (int i = 0; i < 32; ++i) A[i][tid] = cell[(d0 + i) * 256 + tid];
        __syncthreads();
        float partial = 0.f;
#pragma unroll
        for (int k = 0; k < 32; ++k) {
            int hw = sub + 8 * k;
            partial += A[d_loc][hw] * rn[hw];
        }
        ps[tid] = partial; __syncthreads();
        if (tid < 128) ps[tid] += ps[tid + 128];
        __syncthreads();
        if (tid < 64) ps[tid] += ps[tid + 64];
        __syncthreads();
        if (tid < 32)
            VNS[((size_t)gb * 8 + m) * 256 + d0 + tid] = ps[tid] + ps[tid + 32];
    }
}

// K7: beta from SD; em[s][d] = sum_l beta*e; logit2 = <em/||em||, vns>/256.
__global__ __launch_bounds__(256) void k7_em(const float* __restrict__ text,
                                             float* __restrict__ ws) {
    __shared__ float rA[256], rB[256];
    __shared__ float sdv[75];
    __shared__ float segs[5];
    __shared__ float betas[5][15];
    const float* SD = ws + OFF_SD;
    const float* VNS = ws + OFF_VNS;
    float* BETA = ws + OFF_BETA;
    float* LG2 = ws + OFF_LG2;
    int blk = blockIdx.x;
    int m = blk & 7, gb = blk >> 3, g = gb / 5;
    int tid = threadIdx.x;
    if (tid < 75) sdv[tid] = SD[((size_t)gb * 8 + m) * 75 + tid];
    __syncthreads();
    if (tid < 5) {
        float s = 0.f;
        for (int l = 0; l < 15; ++l) s += sdv[tid * 15 + l];
        segs[tid] = s;
    }
    __syncthreads();
    if (tid < 75) {
        float b = sdv[tid] / segs[tid / 15];
        betas[tid / 15][tid % 15] = b;
        BETA[((size_t)gb * 8 + m) * 75 + tid] = b;
    }
    __syncthreads();
    float vns = VNS[((size_t)gb * 8 + m) * 256 + tid];
    for (int s = 0; s < 5; ++s) {
        float em = 0.f;
#pragma unroll
        for (int l = 0; l < 15; ++l)
            em += betas[s][l] * text[((size_t)(g * 5 + s) * 15 + l) * 256 + tid];
        rA[tid] = em * em; rB[tid] = em * vns;
        __syncthreads();
        if (tid < 128) { rA[tid] += rA[tid + 128]; rB[tid] += rB[tid + 128]; }
        __syncthreads();
        if (tid < 64) {
            float a = rA[tid] + rA[tid + 64];
            float b = rB[tid] + rB[tid + 64];
            SHFL_TAIL_ADD(a)
            SHFL_TAIL_ADD(b)
            if (tid == 0)
                LG2[((size_t)gb * 8 + m) * 5 + s] =
                    b / fmaxf(sqrtf(a), 1e-12f) * (1.f / 256.f);
        }
        __syncthreads();  // rA/rB reused next segment
    }
}

// K8: per-g block assembly -> BLK[g]
__global__ __launch_bounds__(256) void k8_final(float* __restrict__ ws) {
    __shared__ float lsm[5][5];
    __shared__ float offsq[5][64];
    __shared__ float regs[5];
    const float* LG = ws + OFF_LG;
    const float* LG2 = ws + OFF_LG2;
    const float* BETA = ws + OFF_BETA;
    float* BLK = ws + OFF_BLK;
    int g = blockIdx.x;
    int tid = threadIdx.x;
    if (tid < 25) {
        int b = tid / 5, s = tid % 5;
        int gb = g * 5 + b;
        float s1 = 0.f;
        for (int l = 0; l < 15; ++l) s1 += expf(LG[gb * 75 + s * 15 + l]);
        float s2 = 0.f;
        for (int mm = 0; mm < 8; ++mm) s2 += expf(LG2[((size_t)gb * 8 + mm) * 5 + s]);
        float l1 = logf(powf(s1, 0.2f) + 1e-10f);
        float l2 = logf(powf(s2, 0.2f) + 1e-10f);
        lsm[b][s] = 10.f * (l1 + l2);
    }
    for (int p = tid; p < 320; p += 256) {
        int b = p >> 6, mn = p & 63, mm = mn >> 3, nn = mn & 7;
        int gb = g * 5 + b;
        const float* bm = BETA + ((size_t)gb * 8 + mm) * 75;
        const float* bn = BETA + ((size_t)gb * 8 + nn) * 75;
        float acc = 0.f;
        for (int t2 = 0; t2 < 75; ++t2) acc += bm[t2] * bn[t2];
        offsq[b][mn] = (mm == nn) ? 0.f : acc * acc;
    }
    __syncthreads();
    if (tid < 5) {
        float s = 0.f;
        for (int i = 0; i < 64; ++i) s += offsq[tid][i];
        regs[tid] = sqrtf(s);
    }
    __syncthreads();
    if (tid == 0) {
        float loss_reg = 0.f;
        for (int b = 0; b < 5; ++b) loss_reg += regs[b];
        loss_reg *= 0.2f;
        float pdq = 0.f, pqd = 0.f;
        for (int i = 0; i < 5; ++i) {
            float rsum = 0.f, csum = 0.f;
            for (int j = 0; j < 5; ++j) { rsum += lsm[i][j]; csum += lsm[j][i]; }
            float di = lsm[i][i];
            pdq += -logf(di / rsum + 1e-10f);
            pqd += -logf(di / csum + 1e-10f);
        }
        BLK[g] = (pdq + pqd) * 0.2f + loss_reg;
    }
}

__global__ void k9_out(const float* __restrict__ ws, float* __restrict__ out) {
    if (threadIdx.x == 0) {
        float s = 0.f;
        for (int g2 = 0; g2 < 8; ++g2) s += ws[OFF_BLK + g2];
        out[0] = s / 9.f;
    }
}

extern "C" void kernel_launch(void* const* d_in, const int* in_sizes, int n_in,
                              void* d_out, int out_size, void* d_ws, size_t ws_size,
                              hipStream_t stream) {
    const float* image = (const float*)d_in[0];
    const float* text  = (const float*)d_in[1];
    float* ws = (float*)d_ws;
    float* out = (float*)d_out;
    hipLaunchKernelGGL(k1_gemm_s,   dim3(640),  dim3(256), 0, stream, image, text, ws);
    hipLaunchKernelGGL(k2_rowstats, dim3(1600), dim3(256), 0, stream, ws);
    hipLaunchKernelGGL(k3_colstats, dim3(3000), dim3(256), 0, stream, ws);
    hipLaunchKernelGGL(k4_vtidal,   dim3(640),  dim3(256), 0, stream, image, ws);
    hipLaunchKernelGGL(k5_logit,    dim3(3000), dim3(256), 0, stream, text, ws);
    hipLaunchKernelGGL(k6_vns,      dim3(320),  dim3(256), 0, stream, image, ws);
    hipLaunchKernelGGL(k7_em,       dim3(320),  dim3(256), 0, stream, text, ws);
    hipLaunchKernelGGL(k8_final,    dim3(8),    dim3(256), 0, stream, ws);
    hipLaunchKernelGGL(k9_out,      dim3(1),    dim3(64),  0, stream, ws, out);
}